// Round 2
// baseline (2001.791 us; speedup 1.0000x reference)
//
#include <hip/hip_runtime.h>
#include <math.h>

#define D 384
#define NHEAD 4
#define CH 96
#define NCLS 20
#define FIN 80

// ============================ CSR build ============================

__global__ void k_zero(int* p, int n) {
    int i = blockIdx.x * blockDim.x + threadIdx.x;
    if (i < n) p[i] = 0;
}

__global__ void k_hist(const int* __restrict__ dst, int* __restrict__ deg, int E) {
    int i = blockIdx.x * blockDim.x + threadIdx.x;
    if (i < E) atomicAdd(&deg[dst[i]], 1);
}

__global__ __launch_bounds__(1024) void k_scan(const int* __restrict__ deg,
                                               int* __restrict__ offs,
                                               int* __restrict__ cursor, int n) {
    __shared__ int sh[1024];
    int t = threadIdx.x;
    int carry = 0;
    int nch = (n + 1023) >> 10;
    for (int c = 0; c < nch; c++) {
        int i = (c << 10) + t;
        int v = (i < n) ? deg[i] : 0;
        sh[t] = v;
        __syncthreads();
        for (int o = 1; o < 1024; o <<= 1) {
            int add = (t >= o) ? sh[t - o] : 0;
            __syncthreads();
            sh[t] += add;
            __syncthreads();
        }
        int excl = carry + sh[t] - v;
        if (i < n) { offs[i] = excl; cursor[i] = excl; }
        carry += sh[1023];
        __syncthreads();
    }
    if (t == 0) offs[n] = carry;
}

__global__ void k_scatter(const int* __restrict__ src, const int* __restrict__ dst,
                          int* __restrict__ cursor, int* __restrict__ csr_src, int E) {
    int i = blockIdx.x * blockDim.x + threadIdx.x;
    if (i < E) {
        int p = atomicAdd(&cursor[dst[i]], 1);
        csr_src[p] = src[i];
    }
}

// ============================ fp32 GEMM: C[M,384] = A[M,K] * W[K,384] ============================
// BM=BN=64, BK=16, 256 threads, 4x4 micro-tile per thread.

__global__ __launch_bounds__(256) void k_gemm(const float* __restrict__ A,
                                              const float* __restrict__ W,
                                              float* __restrict__ Cm, int M, int K) {
    __shared__ float As[16][65];
    __shared__ float Bs[16][64];
    const int t = threadIdx.x;
    const int bm0 = blockIdx.x * 64, bn0 = blockIdx.y * 64;
    const int tm = t >> 4, tn = t & 15;
    const int aRow = t >> 2, aCol = (t & 3) << 2;
    const int bRow = t >> 4, bCol = (t & 15) << 2;
    float acc[4][4] = {};

    for (int k0 = 0; k0 < K; k0 += 16) {
        float4 av = make_float4(0.f, 0.f, 0.f, 0.f);
        int grow = bm0 + aRow;
        if (grow < M) av = *(const float4*)(A + (size_t)grow * K + k0 + aCol);
        As[aCol + 0][aRow] = av.x;
        As[aCol + 1][aRow] = av.y;
        As[aCol + 2][aRow] = av.z;
        As[aCol + 3][aRow] = av.w;
        float4 bv = *(const float4*)(W + (size_t)(k0 + bRow) * D + bn0 + bCol);
        *(float4*)&Bs[bRow][bCol] = bv;
        __syncthreads();
#pragma unroll
        for (int k = 0; k < 16; k++) {
            float a[4], b[4];
#pragma unroll
            for (int i = 0; i < 4; i++) a[i] = As[k][tm * 4 + i];
#pragma unroll
            for (int j = 0; j < 4; j++) b[j] = Bs[k][tn * 4 + j];
#pragma unroll
            for (int i = 0; i < 4; i++)
#pragma unroll
                for (int j = 0; j < 4; j++) acc[i][j] += a[i] * b[j];
        }
        __syncthreads();
    }
#pragma unroll
    for (int i = 0; i < 4; i++) {
        int row = bm0 + tm * 4 + i;
        if (row < M) {
            float4 w4 = make_float4(acc[i][0], acc[i][1], acc[i][2], acc[i][3]);
            *(float4*)(Cm + (size_t)row * D + bn0 + tn * 4) = w4;
        }
    }
}

// ============================ fused GAT node kernel ============================
// One wave (64 lanes) per node. Lane l owns channels [l*6, l*6+6). Lanes
// [h*16,(h+1)*16) form head h (96 channels). Online softmax over in-edges
// (CSR), then + bias, LayerNorm, ELU, store.

__global__ __launch_bounds__(256) void k_gat(const float* __restrict__ XS,
                                             const float* __restrict__ XD,
                                             const float* __restrict__ att,
                                             const float* __restrict__ bias,
                                             const float* __restrict__ gamma,
                                             const float* __restrict__ beta,
                                             const int* __restrict__ offs,
                                             const int* __restrict__ csr_src,
                                             float* __restrict__ Hout, int N) {
    int wave = threadIdx.x >> 6;
    int lane = threadIdx.x & 63;
    int node = blockIdx.x * 4 + wave;
    if (node >= N) return;
    int c0 = lane * 6;

    float xd[6], attr[6];
    const float2* xdp = (const float2*)(XD + (size_t)node * D);
    float2 t0 = xdp[lane * 3 + 0], t1 = xdp[lane * 3 + 1], t2 = xdp[lane * 3 + 2];
    xd[0] = t0.x; xd[1] = t0.y; xd[2] = t1.x; xd[3] = t1.y; xd[4] = t2.x; xd[5] = t2.y;
#pragma unroll
    for (int k = 0; k < 6; k++) attr[k] = att[c0 + k];

    float m = -INFINITY, denom = 0.f;
    float acc[6] = {0.f, 0.f, 0.f, 0.f, 0.f, 0.f};
    int e0 = offs[node], e1 = offs[node + 1];

    for (int e = e0; e < e1; e++) {
        int s = csr_src[e];
        const float2* xsp = (const float2*)(XS + (size_t)s * D);
        float2 a0 = xsp[lane * 3 + 0], a1 = xsp[lane * 3 + 1], a2 = xsp[lane * 3 + 2];
        float xs[6] = {a0.x, a0.y, a1.x, a1.y, a2.x, a2.y};
        float part = 0.f;
#pragma unroll
        for (int k = 0; k < 6; k++) {
            float v = xs[k] + xd[k];
            v = v > 0.f ? v : 0.2f * v;
            part += v * attr[k];
        }
        // reduce across the 16 lanes of this head
#pragma unroll
        for (int o = 1; o < 16; o <<= 1) part += __shfl_xor(part, o, 64);
        float enew = part;
        float nm = fmaxf(m, enew);
        float r = expf(m - nm);   // first iter: expf(-inf)=0
        float p = expf(enew - nm);
        denom = denom * r + p;
#pragma unroll
        for (int k = 0; k < 6; k++) acc[k] = acc[k] * r + p * xs[k];
        m = nm;
    }

    float inv = 1.f / (denom + 1e-16f);
    float v[6];
    float s1 = 0.f;
#pragma unroll
    for (int k = 0; k < 6; k++) { v[k] = acc[k] * inv + bias[c0 + k]; s1 += v[k]; }
#pragma unroll
    for (int o = 1; o < 64; o <<= 1) s1 += __shfl_xor(s1, o, 64);
    float mu = s1 * (1.f / 384.f);
    float s2 = 0.f;
#pragma unroll
    for (int k = 0; k < 6; k++) { float d = v[k] - mu; s2 += d * d; }
#pragma unroll
    for (int o = 1; o < 64; o <<= 1) s2 += __shfl_xor(s2, o, 64);
    float rstd = rsqrtf(s2 * (1.f / 384.f) + 1e-5f);

    float2* hp = (float2*)(Hout + (size_t)node * D);
    float ov[6];
#pragma unroll
    for (int k = 0; k < 6; k++) {
        float y = (v[k] - mu) * rstd * gamma[c0 + k] + beta[c0 + k];
        ov[k] = y > 0.f ? y : expm1f(y);
    }
    hp[lane * 3 + 0] = make_float2(ov[0], ov[1]);
    hp[lane * 3 + 1] = make_float2(ov[2], ov[3]);
    hp[lane * 3 + 2] = make_float2(ov[4], ov[5]);
}

// ============================ classifier head ============================
// 8 nodes per 256-thread block: h@Wc1+bc1 -> relu -> LN -> @Wc2+bc2

__global__ __launch_bounds__(256) void k_head(const float* __restrict__ Hin,
                                              const float* __restrict__ Wc1,
                                              const float* __restrict__ bc1,
                                              const float* __restrict__ gc,
                                              const float* __restrict__ bec,
                                              const float* __restrict__ Wc2,
                                              const float* __restrict__ bc2,
                                              float* __restrict__ out, int N) {
    __shared__ float hs[8][D];
    __shared__ float ys[8][CH];
    __shared__ float mu_s[8], rs_s[8];
    int t = threadIdx.x;
    int n0 = blockIdx.x * 8;

    for (int idx = t; idx < 8 * D; idx += 256) {
        int n = idx / D, k = idx - n * D;
        int row = n0 + n;
        hs[n][k] = (row < N) ? Hin[(size_t)row * D + k] : 0.f;
    }
    __syncthreads();

    if (t < CH) {
        float a[8];
#pragma unroll
        for (int n = 0; n < 8; n++) a[n] = bc1[t];
        for (int k = 0; k < D; k++) {
            float w = Wc1[k * CH + t];
#pragma unroll
            for (int n = 0; n < 8; n++) a[n] += hs[n][k] * w;
        }
#pragma unroll
        for (int n = 0; n < 8; n++) ys[n][t] = fmaxf(a[n], 0.f);
    }
    __syncthreads();

    if (t < 8) {
        float s = 0.f;
        for (int c = 0; c < CH; c++) s += ys[t][c];
        float mu = s * (1.f / CH);
        float q = 0.f;
        for (int c = 0; c < CH; c++) { float d = ys[t][c] - mu; q += d * d; }
        mu_s[t] = mu;
        rs_s[t] = rsqrtf(q * (1.f / CH) + 1e-5f);
    }
    __syncthreads();

    if (t < CH) {
#pragma unroll
        for (int n = 0; n < 8; n++)
            ys[n][t] = (ys[n][t] - mu_s[n]) * rs_s[n] * gc[t] + bec[t];
    }
    __syncthreads();

    if (t < 8 * NCLS) {
        int n = t / NCLS, j = t - n * NCLS;
        float o = bc2[j];
        for (int c = 0; c < CH; c++) o += ys[n][c] * Wc2[c * NCLS + j];
        int row = n0 + n;
        if (row < N) out[(size_t)row * NCLS + j] = o;
    }
}

// ============================ launch ============================

extern "C" void kernel_launch(void* const* d_in, const int* in_sizes, int n_in,
                              void* d_out, int out_size, void* d_ws, size_t ws_size,
                              hipStream_t stream) {
    const float* x        = (const float*)d_in[0];
    const int*   eidx     = (const int*)d_in[1];
    const float* Wsrc[3]  = {(const float*)d_in[2],  (const float*)d_in[8],  (const float*)d_in[14]};
    const float* Wdst[3]  = {(const float*)d_in[3],  (const float*)d_in[9],  (const float*)d_in[15]};
    const float* attw[3]  = {(const float*)d_in[4],  (const float*)d_in[10], (const float*)d_in[16]};
    const float* bia[3]   = {(const float*)d_in[5],  (const float*)d_in[11], (const float*)d_in[17]};
    const float* gam[3]   = {(const float*)d_in[6],  (const float*)d_in[12], (const float*)d_in[18]};
    const float* bet[3]   = {(const float*)d_in[7],  (const float*)d_in[13], (const float*)d_in[19]};
    const float* Wc1 = (const float*)d_in[20];
    const float* bc1 = (const float*)d_in[21];
    const float* gc  = (const float*)d_in[22];
    const float* bec = (const float*)d_in[23];
    const float* Wc2 = (const float*)d_in[24];
    const float* bc2 = (const float*)d_in[25];

    const int N = in_sizes[0] / FIN;
    const int E = in_sizes[1] / 2;
    const int* srcp = eidx;
    const int* dstp = eidx + E;

    // workspace layout (floats then ints): XS, XD, H, offs, cursor, deg, csr_src
    float* XS = (float*)d_ws;
    float* XD = XS + (size_t)N * D;
    float* Hb = XD + (size_t)N * D;
    int* offs    = (int*)(Hb + (size_t)N * D);
    int* cursor  = offs + (N + 1);
    int* deg     = cursor + (N + 1);
    int* csr_src = deg + N;

    // ---- CSR build ----
    k_zero<<<(N + 255) / 256, 256, 0, stream>>>(deg, N);
    k_hist<<<(E + 255) / 256, 256, 0, stream>>>(dstp, deg, E);
    k_scan<<<1, 1024, 0, stream>>>(deg, offs, cursor, N);
    k_scatter<<<(E + 255) / 256, 256, 0, stream>>>(srcp, dstp, cursor, csr_src, E);

    dim3 gg((N + 63) / 64, D / 64);
    int gatGrid = (N + 3) / 4;

    // ---- layer 0 (K = 80) ----
    k_gemm<<<gg, 256, 0, stream>>>(x, Wsrc[0], XS, N, FIN);
    k_gemm<<<gg, 256, 0, stream>>>(x, Wdst[0], XD, N, FIN);
    k_gat<<<gatGrid, 256, 0, stream>>>(XS, XD, attw[0], bia[0], gam[0], bet[0],
                                       offs, csr_src, Hb, N);
    // ---- layers 1,2 (K = 384) ----
    for (int l = 1; l < 3; l++) {
        k_gemm<<<gg, 256, 0, stream>>>(Hb, Wsrc[l], XS, N, D);
        k_gemm<<<gg, 256, 0, stream>>>(Hb, Wdst[l], XD, N, D);
        k_gat<<<gatGrid, 256, 0, stream>>>(XS, XD, attw[l], bia[l], gam[l], bet[l],
                                           offs, csr_src, Hb, N);
    }
    // ---- classifier head ----
    k_head<<<(N + 7) / 8, 256, 0, stream>>>(Hb, Wc1, bc1, gc, bec, Wc2, bc2,
                                            (float*)d_out, N);
}

// Round 6
// 1044.520 us; speedup vs baseline: 1.9165x; 1.9165x over previous
//
#include <hip/hip_runtime.h>
#include <math.h>

#define D 384
#define NCLS 20
#define FIN 80
#define CH 96

typedef unsigned int u32t;
typedef unsigned short u16t;
typedef __attribute__((ext_vector_type(8))) short bf16x8;
typedef __attribute__((ext_vector_type(4))) float f32x4;

__device__ __forceinline__ u16t f2bf(float f) {
    u32t b = __float_as_uint(f);
    u32t r = (b + 0x7FFFu + ((b >> 16) & 1u)) >> 16;
    return (u16t)r;
}
__device__ __forceinline__ float bfl(u32t u) { return __uint_as_float(u << 16); }
__device__ __forceinline__ float bfh(u32t u) { return __uint_as_float(u & 0xFFFF0000u); }

#define GLOAD16(g, l)                                                            \
    __builtin_amdgcn_global_load_lds(                                            \
        (const __attribute__((address_space(1))) void*)(g),                      \
        (__attribute__((address_space(3))) void*)(l), 16, 0, 0)

// ============================ CSR build ============================

__global__ void k_zero(int* p, int n) {
    int i = blockIdx.x * blockDim.x + threadIdx.x;
    if (i < n) p[i] = 0;
}

__global__ void k_hist(const int* __restrict__ dst, int* __restrict__ deg, int E) {
    int i = blockIdx.x * blockDim.x + threadIdx.x;
    if (i < E) atomicAdd(&deg[dst[i]], 1);
}

// 3-phase parallel exclusive scan (nb <= 256 blocks of 256)
__global__ __launch_bounds__(256) void k_scan1(const int* __restrict__ deg,
                                               int* __restrict__ offs,
                                               int* __restrict__ bsum, int n) {
    __shared__ int sh[256];
    int t = threadIdx.x, i = blockIdx.x * 256 + t;
    int v = (i < n) ? deg[i] : 0;
    sh[t] = v;
    __syncthreads();
    for (int o = 1; o < 256; o <<= 1) {
        int a = (t >= o) ? sh[t - o] : 0;
        __syncthreads();
        sh[t] += a;
        __syncthreads();
    }
    if (i < n) offs[i] = sh[t] - v;           // block-local exclusive
    if (t == 255) bsum[blockIdx.x] = sh[255]; // block total
}

__global__ __launch_bounds__(256) void k_scan2(int* __restrict__ bsum, int nb,
                                               int* __restrict__ offs, int n) {
    __shared__ int sh[256];
    int t = threadIdx.x;
    int v = (t < nb) ? bsum[t] : 0;
    sh[t] = v;
    __syncthreads();
    for (int o = 1; o < 256; o <<= 1) {
        int a = (t >= o) ? sh[t - o] : 0;
        __syncthreads();
        sh[t] += a;
        __syncthreads();
    }
    if (t < nb) bsum[t] = sh[t] - v;          // exclusive block offsets
    if (t == 255) offs[n] = sh[255];          // total = E
}

__global__ __launch_bounds__(256) void k_scan3(int* __restrict__ offs,
                                               int* __restrict__ cursor,
                                               const int* __restrict__ bsum, int n) {
    int i = blockIdx.x * 256 + threadIdx.x;
    if (i < n) {
        int o = offs[i] + bsum[blockIdx.x];
        offs[i] = o;
        cursor[i] = o;
    }
}

__global__ void k_scatter(const int* __restrict__ src, const int* __restrict__ dst,
                          int* __restrict__ cursor, int* __restrict__ csr_src, int E) {
    int i = blockIdx.x * blockDim.x + threadIdx.x;
    if (i < E) {
        int p = atomicAdd(&cursor[dst[i]], 1);
        csr_src[p] = src[i];
    }
}

// ============================ fp32 -> bf16 converters ============================

// x [N][80] f32 -> xbf [Mpad][96] bf16, cols 80..95 zero
__global__ void k_cvt_x(const float* __restrict__ x, u16t* __restrict__ xbf, int N) {
    int i = blockIdx.x * 256 + threadIdx.x;
    if (i >= N * 96) return;
    int r = i / 96, c = i - r * 96;
    float v = (c < FIN) ? x[r * FIN + c] : 0.f;
    xbf[i] = f2bf(v);
}

// W [K][384] f32 -> WT [384][Kp] bf16 (transposed), rows k>=K zero
__global__ void k_cvt_wT(const float* __restrict__ W, u16t* __restrict__ WT,
                         int K, int Kp) {
    int i = blockIdx.x * 256 + threadIdx.x;
    if (i >= D * Kp) return;
    int c = i / Kp, k = i - c * Kp;
    float v = (k < K) ? W[(size_t)k * D + c] : 0.f;
    WT[i] = f2bf(v);
}

// ============================ bf16 MFMA GEMM ============================
// C[Mpad,384](bf16) = A[Mpad,Kp](bf16) * BT[384,Kp](bf16, transposed weights)
// 128x128 tile, BK=32, 4 waves (2x2 quadrants of 64x64), mfma 16x16x32 bf16.
// LDS layout [kc(4)][row(128)][8 bf16] -> conflict-free b128 frag reads and
// linear in global_load_lds lane order.

__global__ __launch_bounds__(256) void k_mm(const u16t* __restrict__ A,
                                            const u16t* __restrict__ BT,
                                            u16t* __restrict__ C, int Kp) {
    __shared__ u16t Al[4][128][8];
    __shared__ u16t Bl[4][128][8];
    const int t = threadIdx.x;
    const int wave = t >> 6, lane = t & 63;
    const int wr = wave >> 1, wc = wave & 1;
    const int bm0 = blockIdx.x * 128;
    const int bn0 = blockIdx.y * 128;
    const int col16 = lane & 15, kc = lane >> 4;

    f32x4 acc[4][4] = {};

    // staging: chunk c = wave*128 + i*64 + lane  ->  kc2 = wave, r = i*64+lane
    const u16t* asrc0 = A + (size_t)(bm0 + lane) * Kp + wave * 8;
    const u16t* asrc1 = A + (size_t)(bm0 + 64 + lane) * Kp + wave * 8;
    const u16t* bsrc0 = BT + (size_t)(bn0 + lane) * Kp + wave * 8;
    const u16t* bsrc1 = BT + (size_t)(bn0 + 64 + lane) * Kp + wave * 8;
    u16t* alds0 = &Al[wave][0][0];
    u16t* alds1 = &Al[wave][64][0];
    u16t* blds0 = &Bl[wave][0][0];
    u16t* blds1 = &Bl[wave][64][0];

    for (int k0 = 0; k0 < Kp; k0 += 32) {
        GLOAD16(asrc0 + k0, alds0);
        GLOAD16(asrc1 + k0, alds1);
        GLOAD16(bsrc0 + k0, blds0);
        GLOAD16(bsrc1 + k0, blds1);
        __syncthreads();   // drains vmcnt(0) before barrier (compiler-emitted)

        bf16x8 a[4], b[4];
#pragma unroll
        for (int m = 0; m < 4; m++)
            a[m] = *(const bf16x8*)&Al[kc][wr * 64 + m * 16 + col16][0];
#pragma unroll
        for (int n = 0; n < 4; n++)
            b[n] = *(const bf16x8*)&Bl[kc][wc * 64 + n * 16 + col16][0];
#pragma unroll
        for (int m = 0; m < 4; m++)
#pragma unroll
            for (int n = 0; n < 4; n++)
                acc[m][n] = __builtin_amdgcn_mfma_f32_16x16x32_bf16(
                    a[m], b[n], acc[m][n], 0, 0, 0);
        __syncthreads();   // protect LDS from next-iter overwrite
    }

#pragma unroll
    for (int m = 0; m < 4; m++) {
#pragma unroll
        for (int n = 0; n < 4; n++) {
#pragma unroll
            for (int j = 0; j < 4; j++) {
                int row = bm0 + wr * 64 + m * 16 + (lane >> 4) * 4 + j;
                int col = bn0 + wc * 64 + n * 16 + col16;
                C[(size_t)row * D + col] = f2bf(acc[m][n][j]);
            }
        }
    }
}

// ============================ fused GAT node kernel (bf16 I/O) ============================
// One wave per node; lane owns 6 channels (3 u32 of packed bf16).

__global__ __launch_bounds__(256) void k_gat(const u16t* __restrict__ XS,
                                             const u16t* __restrict__ XD,
                                             const float* __restrict__ att,
                                             const float* __restrict__ bias,
                                             const float* __restrict__ gamma,
                                             const float* __restrict__ beta,
                                             const int* __restrict__ offs,
                                             const int* __restrict__ csr_src,
                                             u16t* __restrict__ Hout,
                                             float* __restrict__ Hf32,
                                             int N) {
    int wave = threadIdx.x >> 6;
    int lane = threadIdx.x & 63;
    int node = blockIdx.x * 4 + wave;
    if (node >= N) return;
    int c0 = lane * 6;

    const u32t* xdp = (const u32t*)XD + (size_t)node * 192 + lane * 3;
    u32t d0 = xdp[0], d1 = xdp[1], d2 = xdp[2];
    float xd[6] = {bfl(d0), bfh(d0), bfl(d1), bfh(d1), bfl(d2), bfh(d2)};
    float attr[6];
#pragma unroll
    for (int k = 0; k < 6; k++) attr[k] = att[c0 + k];

    float m = -INFINITY, denom = 0.f;
    float acc[6] = {0.f, 0.f, 0.f, 0.f, 0.f, 0.f};
    int e0 = offs[node], e1 = offs[node + 1];

    for (int e = e0; e < e1; e++) {
        int s = csr_src[e];
        const u32t* xsp = (const u32t*)XS + (size_t)s * 192 + lane * 3;
        u32t a0 = xsp[0], a1 = xsp[1], a2 = xsp[2];
        float xs[6] = {bfl(a0), bfh(a0), bfl(a1), bfh(a1), bfl(a2), bfh(a2)};
        float part = 0.f;
#pragma unroll
        for (int k = 0; k < 6; k++) {
            float v = xs[k] + xd[k];
            v = v > 0.f ? v : 0.2f * v;
            part += v * attr[k];
        }
#pragma unroll
        for (int o = 1; o < 16; o <<= 1) part += __shfl_xor(part, o, 64);
        float enew = part;
        float nm = fmaxf(m, enew);
        float r = expf(m - nm);
        float p = expf(enew - nm);
        denom = denom * r + p;
#pragma unroll
        for (int k = 0; k < 6; k++) acc[k] = acc[k] * r + p * xs[k];
        m = nm;
    }

    float inv = 1.f / (denom + 1e-16f);
    float v[6];
    float s1 = 0.f;
#pragma unroll
    for (int k = 0; k < 6; k++) { v[k] = acc[k] * inv + bias[c0 + k]; s1 += v[k]; }
#pragma unroll
    for (int o = 1; o < 64; o <<= 1) s1 += __shfl_xor(s1, o, 64);
    float mu = s1 * (1.f / 384.f);
    float s2 = 0.f;
#pragma unroll
    for (int k = 0; k < 6; k++) { float d = v[k] - mu; s2 += d * d; }
#pragma unroll
    for (int o = 1; o < 64; o <<= 1) s2 += __shfl_xor(s2, o, 64);
    float rstd = rsqrtf(s2 * (1.f / 384.f) + 1e-5f);

    float ov[6];
#pragma unroll
    for (int k = 0; k < 6; k++) {
        float y = (v[k] - mu) * rstd * gamma[c0 + k] + beta[c0 + k];
        ov[k] = y > 0.f ? y : expm1f(y);
    }
    u32t w0 = (u32t)f2bf(ov[0]) | ((u32t)f2bf(ov[1]) << 16);
    u32t w1 = (u32t)f2bf(ov[2]) | ((u32t)f2bf(ov[3]) << 16);
    u32t w2 = (u32t)f2bf(ov[4]) | ((u32t)f2bf(ov[5]) << 16);
    u32t* hp = (u32t*)Hout + (size_t)node * 192 + lane * 3;
    hp[0] = w0; hp[1] = w1; hp[2] = w2;

    if (Hf32) {
        float2* fp = (float2*)(Hf32 + (size_t)node * D);
        fp[lane * 3 + 0] = make_float2(ov[0], ov[1]);
        fp[lane * 3 + 1] = make_float2(ov[2], ov[3]);
        fp[lane * 3 + 2] = make_float2(ov[4], ov[5]);
    }
}

// ============================ classifier head (fp32) ============================

__global__ __launch_bounds__(256) void k_head(const float* __restrict__ Hin,
                                              const float* __restrict__ Wc1,
                                              const float* __restrict__ bc1,
                                              const float* __restrict__ gc,
                                              const float* __restrict__ bec,
                                              const float* __restrict__ Wc2,
                                              const float* __restrict__ bc2,
                                              float* __restrict__ out, int N) {
    __shared__ float hs[8][D];
    __shared__ float ys[8][CH];
    __shared__ float mu_s[8], rs_s[8];
    int t = threadIdx.x;
    int n0 = blockIdx.x * 8;

    for (int idx = t; idx < 8 * D; idx += 256) {
        int n = idx / D, k = idx - n * D;
        int row = n0 + n;
        hs[n][k] = (row < N) ? Hin[(size_t)row * D + k] : 0.f;
    }
    __syncthreads();

    if (t < CH) {
        float a[8];
#pragma unroll
        for (int n = 0; n < 8; n++) a[n] = bc1[t];
        for (int k = 0; k < D; k++) {
            float w = Wc1[k * CH + t];
#pragma unroll
            for (int n = 0; n < 8; n++) a[n] += hs[n][k] * w;
        }
#pragma unroll
        for (int n = 0; n < 8; n++) ys[n][t] = fmaxf(a[n], 0.f);
    }
    __syncthreads();

    if (t < 8) {
        float s = 0.f;
        for (int c = 0; c < CH; c++) s += ys[t][c];
        float mu = s * (1.f / CH);
        float q = 0.f;
        for (int c = 0; c < CH; c++) { float d = ys[t][c] - mu; q += d * d; }
        mu_s[t] = mu;
        rs_s[t] = rsqrtf(q * (1.f / CH) + 1e-5f);
    }
    __syncthreads();

    if (t < CH) {
#pragma unroll
        for (int n = 0; n < 8; n++)
            ys[n][t] = (ys[n][t] - mu_s[n]) * rs_s[n] * gc[t] + bec[t];
    }
    __syncthreads();

    if (t < 8 * NCLS) {
        int n = t / NCLS, j = t - n * NCLS;
        float o = bc2[j];
        for (int c = 0; c < CH; c++) o += ys[n][c] * Wc2[c * NCLS + j];
        int row = n0 + n;
        if (row < N) out[(size_t)row * NCLS + j] = o;
    }
}

// ============================ launch ============================

extern "C" void kernel_launch(void* const* d_in, const int* in_sizes, int n_in,
                              void* d_out, int out_size, void* d_ws, size_t ws_size,
                              hipStream_t stream) {
    const float* x        = (const float*)d_in[0];
    const int*   eidx     = (const int*)d_in[1];
    const float* Wsrc[3]  = {(const float*)d_in[2],  (const float*)d_in[8],  (const float*)d_in[14]};
    const float* Wdst[3]  = {(const float*)d_in[3],  (const float*)d_in[9],  (const float*)d_in[15]};
    const float* attw[3]  = {(const float*)d_in[4],  (const float*)d_in[10], (const float*)d_in[16]};
    const float* bia[3]   = {(const float*)d_in[5],  (const float*)d_in[11], (const float*)d_in[17]};
    const float* gam[3]   = {(const float*)d_in[6],  (const float*)d_in[12], (const float*)d_in[18]};
    const float* bet[3]   = {(const float*)d_in[7],  (const float*)d_in[13], (const float*)d_in[19]};
    const float* Wc1 = (const float*)d_in[20];
    const float* bc1 = (const float*)d_in[21];
    const float* gc  = (const float*)d_in[22];
    const float* bec = (const float*)d_in[23];
    const float* Wc2 = (const float*)d_in[24];
    const float* bc2 = (const float*)d_in[25];

    const int N = in_sizes[0] / FIN;
    const int E = in_sizes[1] / 2;
    const int Mpad = ((N + 127) / 128) * 128;
    const int* srcp = eidx;
    const int* dstp = eidx + E;

    // ---- workspace layout ----
    float* Hf32 = (float*)d_ws;                       // N*D f32 (head input)
    u16t* xbf  = (u16t*)(Hf32 + (size_t)N * D);       // Mpad*96
    u16t* XSbf = xbf + (size_t)Mpad * 96;             // Mpad*D
    u16t* XDbf = XSbf + (size_t)Mpad * D;
    u16t* Hbf  = XDbf + (size_t)Mpad * D;
    u16t* WT0s = Hbf + (size_t)Mpad * D;              // [384][96]
    u16t* WT0d = WT0s + 384 * 96;
    u16t* WT1s = WT0d + 384 * 96;                     // [384][384]
    u16t* WT1d = WT1s + 384 * 384;
    u16t* WT2s = WT1d + 384 * 384;
    u16t* WT2d = WT2s + 384 * 384;
    int* offs    = (int*)(WT2d + 384 * 384);
    int* cursor  = offs + (N + 1);
    int* deg     = cursor + (N + 1);
    int* bsum    = deg + N;
    int* csr_src = bsum + 512;

    const int nb = (N + 255) / 256;

    // ---- CSR build ----
    k_zero<<<nb, 256, 0, stream>>>(deg, N);
    k_hist<<<(E + 255) / 256, 256, 0, stream>>>(dstp, deg, E);
    k_scan1<<<nb, 256, 0, stream>>>(deg, offs, bsum, N);
    k_scan2<<<1, 256, 0, stream>>>(bsum, nb, offs, N);
    k_scan3<<<nb, 256, 0, stream>>>(offs, cursor, bsum, N);
    k_scatter<<<(E + 255) / 256, 256, 0, stream>>>(srcp, dstp, cursor, csr_src, E);

    // ---- weight/input conversion ----
    k_cvt_x<<<(N * 96 + 255) / 256, 256, 0, stream>>>(x, xbf, N);
    k_cvt_wT<<<(D * 96 + 255) / 256, 256, 0, stream>>>(Wsrc[0], WT0s, FIN, 96);
    k_cvt_wT<<<(D * 96 + 255) / 256, 256, 0, stream>>>(Wdst[0], WT0d, FIN, 96);
    k_cvt_wT<<<(D * D + 255) / 256, 256, 0, stream>>>(Wsrc[1], WT1s, D, D);
    k_cvt_wT<<<(D * D + 255) / 256, 256, 0, stream>>>(Wdst[1], WT1d, D, D);
    k_cvt_wT<<<(D * D + 255) / 256, 256, 0, stream>>>(Wsrc[2], WT2s, D, D);
    k_cvt_wT<<<(D * D + 255) / 256, 256, 0, stream>>>(Wdst[2], WT2d, D, D);

    dim3 gmm(Mpad / 128, D / 128);
    int gatGrid = (N + 3) / 4;

    // ---- layer 0 (Kp = 96) ----
    k_mm<<<gmm, 256, 0, stream>>>(xbf, WT0s, XSbf, 96);
    k_mm<<<gmm, 256, 0, stream>>>(xbf, WT0d, XDbf, 96);
    k_gat<<<gatGrid, 256, 0, stream>>>(XSbf, XDbf, attw[0], bia[0], gam[0], bet[0],
                                       offs, csr_src, Hbf, (float*)nullptr, N);
    // ---- layer 1 (Kp = 384) ----
    k_mm<<<gmm, 256, 0, stream>>>(Hbf, WT1s, XSbf, D);
    k_mm<<<gmm, 256, 0, stream>>>(Hbf, WT1d, XDbf, D);
    k_gat<<<gatGrid, 256, 0, stream>>>(XSbf, XDbf, attw[1], bia[1], gam[1], bet[1],
                                       offs, csr_src, Hbf, (float*)nullptr, N);
    // ---- layer 2 (Kp = 384, also emit fp32 for head) ----
    k_mm<<<gmm, 256, 0, stream>>>(Hbf, WT2s, XSbf, D);
    k_mm<<<gmm, 256, 0, stream>>>(Hbf, WT2d, XDbf, D);
    k_gat<<<gatGrid, 256, 0, stream>>>(XSbf, XDbf, attw[2], bia[2], gam[2], bet[2],
                                       offs, csr_src, Hbf, Hf32, N);

    // ---- classifier head ----
    k_head<<<(N + 7) / 8, 256, 0, stream>>>(Hf32, Wc1, bc1, gc, bec, Wc2, bc2,
                                            (float*)d_out, N);
}

// Round 7
// 912.636 us; speedup vs baseline: 2.1934x; 1.1445x over previous
//
#include <hip/hip_runtime.h>
#include <math.h>

#define D 384
#define NCLS 20
#define FIN 80
#define CH 96

typedef unsigned int u32t;
typedef unsigned short u16t;
typedef __attribute__((ext_vector_type(8))) short bf16x8;
typedef __attribute__((ext_vector_type(4))) float f32x4;

__device__ __forceinline__ u16t f2bf(float f) {
    u32t b = __float_as_uint(f);
    u32t r = (b + 0x7FFFu + ((b >> 16) & 1u)) >> 16;
    return (u16t)r;
}
__device__ __forceinline__ float bfl(u32t u) { return __uint_as_float(u << 16); }
__device__ __forceinline__ float bfh(u32t u) { return __uint_as_float(u & 0xFFFF0000u); }

#define GLOAD16(g, l)                                                            \
    __builtin_amdgcn_global_load_lds(                                            \
        (const __attribute__((address_space(1))) void*)(g),                      \
        (__attribute__((address_space(3))) void*)(l), 16, 0, 0)

// ============================ CSR build ============================

__global__ void k_zero(int* p, int n) {
    int i = blockIdx.x * blockDim.x + threadIdx.x;
    if (i < n) p[i] = 0;
}

__global__ void k_hist(const int* __restrict__ dst, int* __restrict__ deg, int E) {
    int i = blockIdx.x * blockDim.x + threadIdx.x;
    if (i < E) atomicAdd(&deg[dst[i]], 1);
}

// 3-phase parallel exclusive scan (nb <= 256 blocks of 256)
__global__ __launch_bounds__(256) void k_scan1(const int* __restrict__ deg,
                                               int* __restrict__ offs,
                                               int* __restrict__ bsum, int n) {
    __shared__ int sh[256];
    int t = threadIdx.x, i = blockIdx.x * 256 + t;
    int v = (i < n) ? deg[i] : 0;
    sh[t] = v;
    __syncthreads();
    for (int o = 1; o < 256; o <<= 1) {
        int a = (t >= o) ? sh[t - o] : 0;
        __syncthreads();
        sh[t] += a;
        __syncthreads();
    }
    if (i < n) offs[i] = sh[t] - v;           // block-local exclusive
    if (t == 255) bsum[blockIdx.x] = sh[255]; // block total
}

__global__ __launch_bounds__(256) void k_scan2(int* __restrict__ bsum, int nb,
                                               int* __restrict__ offs, int n) {
    __shared__ int sh[256];
    int t = threadIdx.x;
    int v = (t < nb) ? bsum[t] : 0;
    sh[t] = v;
    __syncthreads();
    for (int o = 1; o < 256; o <<= 1) {
        int a = (t >= o) ? sh[t - o] : 0;
        __syncthreads();
        sh[t] += a;
        __syncthreads();
    }
    if (t < nb) bsum[t] = sh[t] - v;          // exclusive block offsets
    if (t == 255) offs[n] = sh[255];          // total = E
}

__global__ __launch_bounds__(256) void k_scan3(int* __restrict__ offs,
                                               int* __restrict__ cursor,
                                               const int* __restrict__ bsum, int n) {
    int i = blockIdx.x * 256 + threadIdx.x;
    if (i < n) {
        int o = offs[i] + bsum[blockIdx.x];
        offs[i] = o;
        cursor[i] = o;
    }
}

__global__ void k_scatter(const int* __restrict__ src, const int* __restrict__ dst,
                          int* __restrict__ cursor, int* __restrict__ csr_src, int E) {
    int i = blockIdx.x * blockDim.x + threadIdx.x;
    if (i < E) {
        int p = atomicAdd(&cursor[dst[i]], 1);
        csr_src[p] = src[i];
    }
}

// ============================ fp32 -> bf16 converters ============================

// x [N][80] f32 -> xbf [Mpad][96] bf16, cols 80..95 zero
__global__ void k_cvt_x(const float* __restrict__ x, u16t* __restrict__ xbf, int N) {
    int i = blockIdx.x * 256 + threadIdx.x;
    if (i >= N * 96) return;
    int r = i / 96, c = i - r * 96;
    float v = (c < FIN) ? x[r * FIN + c] : 0.f;
    xbf[i] = f2bf(v);
}

// W [K][384] f32 -> WT [384][Kp] bf16 (transposed), rows k>=K zero
__global__ void k_cvt_wT(const float* __restrict__ W, u16t* __restrict__ WT,
                         int K, int Kp) {
    int i = blockIdx.x * 256 + threadIdx.x;
    if (i >= D * Kp) return;
    int c = i / Kp, k = i - c * Kp;
    float v = (k < K) ? W[(size_t)k * D + c] : 0.f;
    WT[i] = f2bf(v);
}

// Wc1 [384][96] f32 -> Wc1T [128][384] bf16 (transposed), rows c>=96 zero
__global__ void k_cvt_wc1T(const float* __restrict__ W, u16t* __restrict__ WT) {
    int i = blockIdx.x * 256 + threadIdx.x;
    if (i >= 128 * D) return;
    int c = i / D, k = i - c * D;
    float v = (c < CH) ? W[(size_t)k * CH + c] : 0.f;
    WT[i] = f2bf(v);
}

// ============================ bf16 MFMA GEMM ============================
// C[Mpad,384](bf16) = A[Mpad,Kp](bf16) * BT[384,Kp](bf16, transposed weights)
// 128x128 tile, BK=32, 4 waves (2x2 quadrants of 64x64), mfma 16x16x32 bf16.

__global__ __launch_bounds__(256) void k_mm(const u16t* __restrict__ A,
                                            const u16t* __restrict__ BT,
                                            u16t* __restrict__ C, int Kp) {
    __shared__ u16t Al[4][128][8];
    __shared__ u16t Bl[4][128][8];
    const int t = threadIdx.x;
    const int wave = t >> 6, lane = t & 63;
    const int wr = wave >> 1, wc = wave & 1;
    const int bm0 = blockIdx.x * 128;
    const int bn0 = blockIdx.y * 128;
    const int col16 = lane & 15, kc = lane >> 4;

    f32x4 acc[4][4] = {};

    const u16t* asrc0 = A + (size_t)(bm0 + lane) * Kp + wave * 8;
    const u16t* asrc1 = A + (size_t)(bm0 + 64 + lane) * Kp + wave * 8;
    const u16t* bsrc0 = BT + (size_t)(bn0 + lane) * Kp + wave * 8;
    const u16t* bsrc1 = BT + (size_t)(bn0 + 64 + lane) * Kp + wave * 8;
    u16t* alds0 = &Al[wave][0][0];
    u16t* alds1 = &Al[wave][64][0];
    u16t* blds0 = &Bl[wave][0][0];
    u16t* blds1 = &Bl[wave][64][0];

    for (int k0 = 0; k0 < Kp; k0 += 32) {
        GLOAD16(asrc0 + k0, alds0);
        GLOAD16(asrc1 + k0, alds1);
        GLOAD16(bsrc0 + k0, blds0);
        GLOAD16(bsrc1 + k0, blds1);
        __syncthreads();

        bf16x8 a[4], b[4];
#pragma unroll
        for (int m = 0; m < 4; m++)
            a[m] = *(const bf16x8*)&Al[kc][wr * 64 + m * 16 + col16][0];
#pragma unroll
        for (int n = 0; n < 4; n++)
            b[n] = *(const bf16x8*)&Bl[kc][wc * 64 + n * 16 + col16][0];
#pragma unroll
        for (int m = 0; m < 4; m++)
#pragma unroll
            for (int n = 0; n < 4; n++)
                acc[m][n] = __builtin_amdgcn_mfma_f32_16x16x32_bf16(
                    a[m], b[n], acc[m][n], 0, 0, 0);
        __syncthreads();
    }

#pragma unroll
    for (int m = 0; m < 4; m++) {
#pragma unroll
        for (int n = 0; n < 4; n++) {
#pragma unroll
            for (int j = 0; j < 4; j++) {
                int row = bm0 + wr * 64 + m * 16 + (lane >> 4) * 4 + j;
                int col = bn0 + wc * 64 + n * 16 + col16;
                C[(size_t)row * D + col] = f2bf(acc[m][n][j]);
            }
        }
    }
}

// ============================ head GEMM: Yh[Mpad,96] = relu(Hbf @ Wc1 + bc1) ============================
// Same structure as k_mm; BT is Wc1T [128][384] (rows 96..127 zero); f32 out.

__global__ __launch_bounds__(256) void k_mmh(const u16t* __restrict__ A,
                                             const u16t* __restrict__ BT,
                                             const float* __restrict__ bc1,
                                             float* __restrict__ Yh) {
    __shared__ u16t Al[4][128][8];
    __shared__ u16t Bl[4][128][8];
    const int t = threadIdx.x;
    const int wave = t >> 6, lane = t & 63;
    const int wr = wave >> 1, wc = wave & 1;
    const int bm0 = blockIdx.x * 128;
    const int col16 = lane & 15, kc = lane >> 4;

    f32x4 acc[4][4] = {};

    const u16t* asrc0 = A + (size_t)(bm0 + lane) * D + wave * 8;
    const u16t* asrc1 = A + (size_t)(bm0 + 64 + lane) * D + wave * 8;
    const u16t* bsrc0 = BT + (size_t)lane * D + wave * 8;
    const u16t* bsrc1 = BT + (size_t)(64 + lane) * D + wave * 8;
    u16t* alds0 = &Al[wave][0][0];
    u16t* alds1 = &Al[wave][64][0];
    u16t* blds0 = &Bl[wave][0][0];
    u16t* blds1 = &Bl[wave][64][0];

    for (int k0 = 0; k0 < D; k0 += 32) {
        GLOAD16(asrc0 + k0, alds0);
        GLOAD16(asrc1 + k0, alds1);
        GLOAD16(bsrc0 + k0, blds0);
        GLOAD16(bsrc1 + k0, blds1);
        __syncthreads();

        bf16x8 a[4], b[4];
#pragma unroll
        for (int m = 0; m < 4; m++)
            a[m] = *(const bf16x8*)&Al[kc][wr * 64 + m * 16 + col16][0];
#pragma unroll
        for (int n = 0; n < 4; n++)
            b[n] = *(const bf16x8*)&Bl[kc][wc * 64 + n * 16 + col16][0];
#pragma unroll
        for (int m = 0; m < 4; m++)
#pragma unroll
            for (int n = 0; n < 4; n++)
                acc[m][n] = __builtin_amdgcn_mfma_f32_16x16x32_bf16(
                    a[m], b[n], acc[m][n], 0, 0, 0);
        __syncthreads();
    }

#pragma unroll
    for (int m = 0; m < 4; m++) {
#pragma unroll
        for (int n = 0; n < 4; n++) {
            int col = wc * 64 + n * 16 + col16;
            if (col < CH) {
                float bc = bc1[col];
#pragma unroll
                for (int j = 0; j < 4; j++) {
                    int row = bm0 + wr * 64 + m * 16 + (lane >> 4) * 4 + j;
                    Yh[(size_t)row * CH + col] = fmaxf(acc[m][n][j] + bc, 0.f);
                }
            }
        }
    }
}

// ============================ fused GAT node kernel (bf16 I/O) ============================

__global__ __launch_bounds__(256) void k_gat(const u16t* __restrict__ XS,
                                             const u16t* __restrict__ XD,
                                             const float* __restrict__ att,
                                             const float* __restrict__ bias,
                                             const float* __restrict__ gamma,
                                             const float* __restrict__ beta,
                                             const int* __restrict__ offs,
                                             const int* __restrict__ csr_src,
                                             u16t* __restrict__ Hout,
                                             int N) {
    int wave = threadIdx.x >> 6;
    int lane = threadIdx.x & 63;
    int node = blockIdx.x * 4 + wave;
    if (node >= N) return;
    int c0 = lane * 6;

    const u32t* xdp = (const u32t*)XD + (size_t)node * 192 + lane * 3;
    u32t d0 = xdp[0], d1 = xdp[1], d2 = xdp[2];
    float xd[6] = {bfl(d0), bfh(d0), bfl(d1), bfh(d1), bfl(d2), bfh(d2)};
    float attr[6];
#pragma unroll
    for (int k = 0; k < 6; k++) attr[k] = att[c0 + k];

    float m = -INFINITY, denom = 0.f;
    float acc[6] = {0.f, 0.f, 0.f, 0.f, 0.f, 0.f};
    int e0 = offs[node], e1 = offs[node + 1];

    for (int e = e0; e < e1; e++) {
        int s = csr_src[e];
        const u32t* xsp = (const u32t*)XS + (size_t)s * 192 + lane * 3;
        u32t a0 = xsp[0], a1 = xsp[1], a2 = xsp[2];
        float xs[6] = {bfl(a0), bfh(a0), bfl(a1), bfh(a1), bfl(a2), bfh(a2)};
        float part = 0.f;
#pragma unroll
        for (int k = 0; k < 6; k++) {
            float v = xs[k] + xd[k];
            v = v > 0.f ? v : 0.2f * v;
            part += v * attr[k];
        }
#pragma unroll
        for (int o = 1; o < 16; o <<= 1) part += __shfl_xor(part, o, 64);
        float enew = part;
        float nm = fmaxf(m, enew);
        float r = expf(m - nm);
        float p = expf(enew - nm);
        denom = denom * r + p;
#pragma unroll
        for (int k = 0; k < 6; k++) acc[k] = acc[k] * r + p * xs[k];
        m = nm;
    }

    float inv = 1.f / (denom + 1e-16f);
    float v[6];
    float s1 = 0.f;
#pragma unroll
    for (int k = 0; k < 6; k++) { v[k] = acc[k] * inv + bias[c0 + k]; s1 += v[k]; }
#pragma unroll
    for (int o = 1; o < 64; o <<= 1) s1 += __shfl_xor(s1, o, 64);
    float mu = s1 * (1.f / 384.f);
    float s2 = 0.f;
#pragma unroll
    for (int k = 0; k < 6; k++) { float d = v[k] - mu; s2 += d * d; }
#pragma unroll
    for (int o = 1; o < 64; o <<= 1) s2 += __shfl_xor(s2, o, 64);
    float rstd = rsqrtf(s2 * (1.f / 384.f) + 1e-5f);

    float ov[6];
#pragma unroll
    for (int k = 0; k < 6; k++) {
        float y = (v[k] - mu) * rstd * gamma[c0 + k] + beta[c0 + k];
        ov[k] = y > 0.f ? y : expm1f(y);
    }
    u32t w0 = (u32t)f2bf(ov[0]) | ((u32t)f2bf(ov[1]) << 16);
    u32t w1 = (u32t)f2bf(ov[2]) | ((u32t)f2bf(ov[3]) << 16);
    u32t w2 = (u32t)f2bf(ov[4]) | ((u32t)f2bf(ov[5]) << 16);
    u32t* hp = (u32t*)Hout + (size_t)node * 192 + lane * 3;
    hp[0] = w0; hp[1] = w1; hp[2] = w2;
}

// ============================ LN + Wc2 output ============================
// 8 nodes/block, 32 threads/node. LN over 96 via 32-lane shuffle reduce,
// then out[20] = ln . Wc2 + bc2 with Wc2 staged in LDS.

__global__ __launch_bounds__(256) void k_lnout(const float* __restrict__ Yh,
                                               const float* __restrict__ gc,
                                               const float* __restrict__ bec,
                                               const float* __restrict__ Wc2,
                                               const float* __restrict__ bc2,
                                               float* __restrict__ out, int N) {
    __shared__ float w2[CH * NCLS];
    __shared__ float ln[8][CH];
    int t = threadIdx.x;
    int g = t >> 5, tl = t & 31;
    int node = blockIdx.x * 8 + g;

    for (int i = t; i < CH * NCLS; i += 256) w2[i] = Wc2[i];

    if (node < N) {
        const float* yp = Yh + (size_t)node * CH;
        float y0 = yp[tl], y1 = yp[32 + tl], y2 = yp[64 + tl];
        float s = y0 + y1 + y2;
#pragma unroll
        for (int o = 1; o < 32; o <<= 1) s += __shfl_xor(s, o, 32);
        float mu = s * (1.f / CH);
        float d0 = y0 - mu, d1 = y1 - mu, d2 = y2 - mu;
        float q = d0 * d0 + d1 * d1 + d2 * d2;
#pragma unroll
        for (int o = 1; o < 32; o <<= 1) q += __shfl_xor(q, o, 32);
        float rstd = rsqrtf(q * (1.f / CH) + 1e-5f);
        ln[g][tl]      = d0 * rstd * gc[tl]      + bec[tl];
        ln[g][32 + tl] = d1 * rstd * gc[32 + tl] + bec[32 + tl];
        ln[g][64 + tl] = d2 * rstd * gc[64 + tl] + bec[64 + tl];
    }
    __syncthreads();

    if (node < N && tl < NCLS) {
        float o = bc2[tl];
        for (int c = 0; c < CH; c++) o += ln[g][c] * w2[c * NCLS + tl];
        out[(size_t)node * NCLS + tl] = o;
    }
}

// ============================ launch ============================

extern "C" void kernel_launch(void* const* d_in, const int* in_sizes, int n_in,
                              void* d_out, int out_size, void* d_ws, size_t ws_size,
                              hipStream_t stream) {
    const float* x        = (const float*)d_in[0];
    const int*   eidx     = (const int*)d_in[1];
    const float* Wsrc[3]  = {(const float*)d_in[2],  (const float*)d_in[8],  (const float*)d_in[14]};
    const float* Wdst[3]  = {(const float*)d_in[3],  (const float*)d_in[9],  (const float*)d_in[15]};
    const float* attw[3]  = {(const float*)d_in[4],  (const float*)d_in[10], (const float*)d_in[16]};
    const float* bia[3]   = {(const float*)d_in[5],  (const float*)d_in[11], (const float*)d_in[17]};
    const float* gam[3]   = {(const float*)d_in[6],  (const float*)d_in[12], (const float*)d_in[18]};
    const float* bet[3]   = {(const float*)d_in[7],  (const float*)d_in[13], (const float*)d_in[19]};
    const float* Wc1 = (const float*)d_in[20];
    const float* bc1 = (const float*)d_in[21];
    const float* gc  = (const float*)d_in[22];
    const float* bec = (const float*)d_in[23];
    const float* Wc2 = (const float*)d_in[24];
    const float* bc2 = (const float*)d_in[25];

    const int N = in_sizes[0] / FIN;
    const int E = in_sizes[1] / 2;
    const int Mpad = ((N + 127) / 128) * 128;
    const int* srcp = eidx;
    const int* dstp = eidx + E;

    // ---- workspace layout ----
    u16t* xbf  = (u16t*)d_ws;                         // Mpad*96
    u16t* XSbf = xbf + (size_t)Mpad * 96;             // Mpad*D
    u16t* XDbf = XSbf + (size_t)Mpad * D;
    u16t* Hbf  = XDbf + (size_t)Mpad * D;
    u16t* WT0s = Hbf + (size_t)Mpad * D;              // [384][96]
    u16t* WT0d = WT0s + 384 * 96;
    u16t* WT1s = WT0d + 384 * 96;                     // [384][384]
    u16t* WT1d = WT1s + 384 * 384;
    u16t* WT2s = WT1d + 384 * 384;
    u16t* WT2d = WT2s + 384 * 384;
    u16t* Wc1T = WT2d + 384 * 384;                    // [128][384]
    float* Yh  = (float*)(Wc1T + 128 * 384);          // Mpad*96 f32
    int* offs    = (int*)(Yh + (size_t)Mpad * CH);
    int* cursor  = offs + (N + 1);
    int* deg     = cursor + (N + 1);
    int* bsum    = deg + N;
    int* csr_src = bsum + 512;

    const int nb = (N + 255) / 256;

    // ---- CSR build ----
    k_zero<<<nb, 256, 0, stream>>>(deg, N);
    k_hist<<<(E + 255) / 256, 256, 0, stream>>>(dstp, deg, E);
    k_scan1<<<nb, 256, 0, stream>>>(deg, offs, bsum, N);
    k_scan2<<<1, 256, 0, stream>>>(bsum, nb, offs, N);
    k_scan3<<<nb, 256, 0, stream>>>(offs, cursor, bsum, N);
    k_scatter<<<(E + 255) / 256, 256, 0, stream>>>(srcp, dstp, cursor, csr_src, E);

    // ---- weight/input conversion ----
    k_cvt_x<<<(N * 96 + 255) / 256, 256, 0, stream>>>(x, xbf, N);
    k_cvt_wT<<<(D * 96 + 255) / 256, 256, 0, stream>>>(Wsrc[0], WT0s, FIN, 96);
    k_cvt_wT<<<(D * 96 + 255) / 256, 256, 0, stream>>>(Wdst[0], WT0d, FIN, 96);
    k_cvt_wT<<<(D * D + 255) / 256, 256, 0, stream>>>(Wsrc[1], WT1s, D, D);
    k_cvt_wT<<<(D * D + 255) / 256, 256, 0, stream>>>(Wdst[1], WT1d, D, D);
    k_cvt_wT<<<(D * D + 255) / 256, 256, 0, stream>>>(Wsrc[2], WT2s, D, D);
    k_cvt_wT<<<(D * D + 255) / 256, 256, 0, stream>>>(Wdst[2], WT2d, D, D);
    k_cvt_wc1T<<<(128 * D + 255) / 256, 256, 0, stream>>>(Wc1, Wc1T);

    dim3 gmm(Mpad / 128, D / 128);
    int gatGrid = (N + 3) / 4;

    // ---- layer 0 (Kp = 96) ----
    k_mm<<<gmm, 256, 0, stream>>>(xbf, WT0s, XSbf, 96);
    k_mm<<<gmm, 256, 0, stream>>>(xbf, WT0d, XDbf, 96);
    k_gat<<<gatGrid, 256, 0, stream>>>(XSbf, XDbf, attw[0], bia[0], gam[0], bet[0],
                                       offs, csr_src, Hbf, N);
    // ---- layer 1 (Kp = 384) ----
    k_mm<<<gmm, 256, 0, stream>>>(Hbf, WT1s, XSbf, D);
    k_mm<<<gmm, 256, 0, stream>>>(Hbf, WT1d, XDbf, D);
    k_gat<<<gatGrid, 256, 0, stream>>>(XSbf, XDbf, attw[1], bia[1], gam[1], bet[1],
                                       offs, csr_src, Hbf, N);
    // ---- layer 2 (Kp = 384) ----
    k_mm<<<gmm, 256, 0, stream>>>(Hbf, WT2s, XSbf, D);
    k_mm<<<gmm, 256, 0, stream>>>(Hbf, WT2d, XDbf, D);
    k_gat<<<gatGrid, 256, 0, stream>>>(XSbf, XDbf, attw[2], bia[2], gam[2], bet[2],
                                       offs, csr_src, Hbf, N);

    // ---- classifier head: MFMA GEMM + LN/out ----
    k_mmh<<<Mpad / 128, 256, 0, stream>>>(Hbf, Wc1T, bc1, Yh);
    k_lnout<<<(N + 7) / 8, 256, 0, stream>>>(Yh, gc, bec, Wc2, bc2,
                                             (float*)d_out, N);
}

// Round 9
// 865.488 us; speedup vs baseline: 2.3129x; 1.0545x over previous
//
#include <hip/hip_runtime.h>
#include <math.h>

#define D 384
#define NCLS 20
#define FIN 80
#define CH 96

typedef unsigned int u32t;
typedef unsigned short u16t;
typedef __attribute__((ext_vector_type(8))) short bf16x8;
typedef __attribute__((ext_vector_type(4))) float f32x4;

__device__ __forceinline__ u16t f2bf(float f) {
    u32t b = __float_as_uint(f);
    u32t r = (b + 0x7FFFu + ((b >> 16) & 1u)) >> 16;
    return (u16t)r;
}
__device__ __forceinline__ float bfl(u32t u) { return __uint_as_float(u << 16); }
__device__ __forceinline__ float bfh(u32t u) { return __uint_as_float(u & 0xFFFF0000u); }

#define GLOAD16(g, l)                                                            \
    __builtin_amdgcn_global_load_lds(                                            \
        (const __attribute__((address_space(1))) void*)(g),                      \
        (__attribute__((address_space(3))) void*)(l), 16, 0, 0)

// ============================ CSR build ============================

__global__ void k_zero(int* p, int n) {
    int i = blockIdx.x * blockDim.x + threadIdx.x;
    if (i < n) p[i] = 0;
}

__global__ void k_hist(const int* __restrict__ dst, int* __restrict__ deg, int E) {
    int i = blockIdx.x * blockDim.x + threadIdx.x;
    if (i < E) atomicAdd(&deg[dst[i]], 1);
}

// 3-phase parallel exclusive scan (nb <= 256 blocks of 256)
__global__ __launch_bounds__(256) void k_scan1(const int* __restrict__ deg,
                                               int* __restrict__ offs,
                                               int* __restrict__ bsum, int n) {
    __shared__ int sh[256];
    int t = threadIdx.x, i = blockIdx.x * 256 + t;
    int v = (i < n) ? deg[i] : 0;
    sh[t] = v;
    __syncthreads();
    for (int o = 1; o < 256; o <<= 1) {
        int a = (t >= o) ? sh[t - o] : 0;
        __syncthreads();
        sh[t] += a;
        __syncthreads();
    }
    if (i < n) offs[i] = sh[t] - v;
    if (t == 255) bsum[blockIdx.x] = sh[255];
}

__global__ __launch_bounds__(256) void k_scan2(int* __restrict__ bsum, int nb,
                                               int* __restrict__ offs, int n) {
    __shared__ int sh[256];
    int t = threadIdx.x;
    int v = (t < nb) ? bsum[t] : 0;
    sh[t] = v;
    __syncthreads();
    for (int o = 1; o < 256; o <<= 1) {
        int a = (t >= o) ? sh[t - o] : 0;
        __syncthreads();
        sh[t] += a;
        __syncthreads();
    }
    if (t < nb) bsum[t] = sh[t] - v;
    if (t == 255) offs[n] = sh[255];
}

__global__ __launch_bounds__(256) void k_scan3(int* __restrict__ offs,
                                               int* __restrict__ cursor,
                                               const int* __restrict__ bsum, int n) {
    int i = blockIdx.x * 256 + threadIdx.x;
    if (i < n) {
        int o = offs[i] + bsum[blockIdx.x];
        offs[i] = o;
        cursor[i] = o;
    }
}

// stores PRE-MULTIPLIED source row offset (src * 384 u32 = row in XSXD)
__global__ void k_scatter(const int* __restrict__ src, const int* __restrict__ dst,
                          int* __restrict__ cursor, int* __restrict__ csr_srcb, int E) {
    int i = blockIdx.x * blockDim.x + threadIdx.x;
    if (i < E) {
        int p = atomicAdd(&cursor[dst[i]], 1);
        csr_srcb[p] = src[i] * 384;
    }
}

// ============================ fp32 -> bf16 converters ============================

__global__ void k_cvt_x(const float* __restrict__ x, u16t* __restrict__ xbf, int N) {
    int i = blockIdx.x * 256 + threadIdx.x;
    if (i >= N * 96) return;
    int r = i / 96, c = i - r * 96;
    float v = (c < FIN) ? x[r * FIN + c] : 0.f;
    xbf[i] = f2bf(v);
}

__global__ void k_cvt_wT(const float* __restrict__ W, u16t* __restrict__ WT,
                         int K, int Kp) {
    int i = blockIdx.x * 256 + threadIdx.x;
    if (i >= D * Kp) return;
    int c = i / Kp, k = i - c * Kp;
    float v = (k < K) ? W[(size_t)k * D + c] : 0.f;
    WT[i] = f2bf(v);
}

__global__ void k_cvt_wc1T(const float* __restrict__ W, u16t* __restrict__ WT) {
    int i = blockIdx.x * 256 + threadIdx.x;
    if (i >= 128 * D) return;
    int c = i / D, k = i - c * D;
    float v = (c < CH) ? W[(size_t)k * CH + c] : 0.f;
    WT[i] = f2bf(v);
}

// ============================ bf16 MFMA GEMM ============================
// C[Mpad, ostride](bf16), cols [0,NB*128): C = A[Mpad,Kp] * BT[NB*128, Kp]
// 128x128 tile, BK=32, 4 waves (2x2 quadrants of 64x64), mfma 16x16x32 bf16.

__global__ __launch_bounds__(256) void k_mm(const u16t* __restrict__ A,
                                            const u16t* __restrict__ BT,
                                            u16t* __restrict__ C, int Kp, int ostride) {
    __shared__ u16t Al[4][128][8];
    __shared__ u16t Bl[4][128][8];
    const int t = threadIdx.x;
    const int wave = t >> 6, lane = t & 63;
    const int wr = wave >> 1, wc = wave & 1;
    const int bm0 = blockIdx.x * 128;
    const int bn0 = blockIdx.y * 128;
    const int col16 = lane & 15, kc = lane >> 4;

    f32x4 acc[4][4] = {};

    const u16t* asrc0 = A + (size_t)(bm0 + lane) * Kp + wave * 8;
    const u16t* asrc1 = A + (size_t)(bm0 + 64 + lane) * Kp + wave * 8;
    const u16t* bsrc0 = BT + (size_t)(bn0 + lane) * Kp + wave * 8;
    const u16t* bsrc1 = BT + (size_t)(bn0 + 64 + lane) * Kp + wave * 8;
    u16t* alds0 = &Al[wave][0][0];
    u16t* alds1 = &Al[wave][64][0];
    u16t* blds0 = &Bl[wave][0][0];
    u16t* blds1 = &Bl[wave][64][0];

    for (int k0 = 0; k0 < Kp; k0 += 32) {
        GLOAD16(asrc0 + k0, alds0);
        GLOAD16(asrc1 + k0, alds1);
        GLOAD16(bsrc0 + k0, blds0);
        GLOAD16(bsrc1 + k0, blds1);
        __syncthreads();

        bf16x8 a[4], b[4];
#pragma unroll
        for (int m = 0; m < 4; m++)
            a[m] = *(const bf16x8*)&Al[kc][wr * 64 + m * 16 + col16][0];
#pragma unroll
        for (int n = 0; n < 4; n++)
            b[n] = *(const bf16x8*)&Bl[kc][wc * 64 + n * 16 + col16][0];
#pragma unroll
        for (int m = 0; m < 4; m++)
#pragma unroll
            for (int n = 0; n < 4; n++)
                acc[m][n] = __builtin_amdgcn_mfma_f32_16x16x32_bf16(
                    a[m], b[n], acc[m][n], 0, 0, 0);
        __syncthreads();
    }

#pragma unroll
    for (int m = 0; m < 4; m++) {
#pragma unroll
        for (int n = 0; n < 4; n++) {
#pragma unroll
            for (int j = 0; j < 4; j++) {
                int row = bm0 + wr * 64 + m * 16 + (lane >> 4) * 4 + j;
                int col = bn0 + wc * 64 + n * 16 + col16;
                C[(size_t)row * ostride + col] = f2bf(acc[m][n][j]);
            }
        }
    }
}

// ============================ head GEMM: Yh[Mpad,96] = relu(Hbf @ Wc1 + bc1) ============================

__global__ __launch_bounds__(256) void k_mmh(const u16t* __restrict__ A,
                                             const u16t* __restrict__ BT,
                                             const float* __restrict__ bc1,
                                             float* __restrict__ Yh) {
    __shared__ u16t Al[4][128][8];
    __shared__ u16t Bl[4][128][8];
    const int t = threadIdx.x;
    const int wave = t >> 6, lane = t & 63;
    const int wr = wave >> 1, wc = wave & 1;
    const int bm0 = blockIdx.x * 128;
    const int col16 = lane & 15, kc = lane >> 4;

    f32x4 acc[4][4] = {};

    const u16t* asrc0 = A + (size_t)(bm0 + lane) * D + wave * 8;
    const u16t* asrc1 = A + (size_t)(bm0 + 64 + lane) * D + wave * 8;
    const u16t* bsrc0 = BT + (size_t)lane * D + wave * 8;
    const u16t* bsrc1 = BT + (size_t)(64 + lane) * D + wave * 8;
    u16t* alds0 = &Al[wave][0][0];
    u16t* alds1 = &Al[wave][64][0];
    u16t* blds0 = &Bl[wave][0][0];
    u16t* blds1 = &Bl[wave][64][0];

    for (int k0 = 0; k0 < D; k0 += 32) {
        GLOAD16(asrc0 + k0, alds0);
        GLOAD16(asrc1 + k0, alds1);
        GLOAD16(bsrc0 + k0, blds0);
        GLOAD16(bsrc1 + k0, blds1);
        __syncthreads();

        bf16x8 a[4], b[4];
#pragma unroll
        for (int m = 0; m < 4; m++)
            a[m] = *(const bf16x8*)&Al[kc][wr * 64 + m * 16 + col16][0];
#pragma unroll
        for (int n = 0; n < 4; n++)
            b[n] = *(const bf16x8*)&Bl[kc][wc * 64 + n * 16 + col16][0];
#pragma unroll
        for (int m = 0; m < 4; m++)
#pragma unroll
            for (int n = 0; n < 4; n++)
                acc[m][n] = __builtin_amdgcn_mfma_f32_16x16x32_bf16(
                    a[m], b[n], acc[m][n], 0, 0, 0);
        __syncthreads();
    }

#pragma unroll
    for (int m = 0; m < 4; m++) {
#pragma unroll
        for (int n = 0; n < 4; n++) {
            int col = wc * 64 + n * 16 + col16;
            if (col < CH) {
                float bc = bc1[col];
#pragma unroll
                for (int j = 0; j < 4; j++) {
                    int row = bm0 + wr * 64 + m * 16 + (lane >> 4) * 4 + j;
                    Yh[(size_t)row * CH + col] = fmaxf(acc[m][n][j] + bc, 0.f);
                }
            }
        }
    }
}

// ============================ fused GAT node kernel ============================
// XSXD [Mpad][768] bf16: cols 0..383 = Wsrc*h, 384..767 = Wdst*h.
// One wave per node; lane owns 6 channels. Defer-max online softmax (THR=8):
// alpha = exp(e-m)/sum exp(e-m) is exact for any reference m; rescale only
// when a new score exceeds m+8 (wave-uniform branch, rare) -> common path is
// 1 sub + 1 v_exp + 1 add + 6 fma per edge.

__global__ __launch_bounds__(256) void k_gat(const u32t* __restrict__ XSXD,
                                             const float* __restrict__ att,
                                             const float* __restrict__ bias,
                                             const float* __restrict__ gamma,
                                             const float* __restrict__ beta,
                                             const int* __restrict__ offs,
                                             const int* __restrict__ csr_srcb,
                                             u16t* __restrict__ Hout,
                                             int N) {
    int wave = threadIdx.x >> 6;
    int lane = threadIdx.x & 63;
    int node = blockIdx.x * 4 + wave;
    if (node >= N) return;
    int c0 = lane * 6;
    int lo3 = lane * 3;

    const u32t* xdp = XSXD + (size_t)node * 384 + 192 + lo3;
    u32t d0 = xdp[0], d1 = xdp[1], d2 = xdp[2];
    float xd[6] = {bfl(d0), bfh(d0), bfl(d1), bfh(d1), bfl(d2), bfh(d2)};
    float attr[6];
#pragma unroll
    for (int k = 0; k < 6; k++) attr[k] = att[c0 + k];

    float m = -INFINITY, denom = 0.f;
    float acc[6] = {0.f, 0.f, 0.f, 0.f, 0.f, 0.f};
    int e0 = offs[node], e1 = offs[node + 1];

    for (int e = e0; e < e1; e++) {
        const u32t* xsp = XSXD + (u32t)csr_srcb[e] + lo3;
        u32t a0 = xsp[0], a1 = xsp[1], a2 = xsp[2];
        float xs[6] = {bfl(a0), bfh(a0), bfl(a1), bfh(a1), bfl(a2), bfh(a2)};
        float part = 0.f;
#pragma unroll
        for (int k = 0; k < 6; k++) {
            float v = xs[k] + xd[k];
            part = fmaf(fmaxf(v, 0.2f * v), attr[k], part);
        }
#pragma unroll
        for (int o = 1; o < 16; o <<= 1) part += __shfl_xor(part, o, 64);

        if (__builtin_expect(__any(part - m > 8.0f), 0)) {
            float nm = fmaxf(m, part);
            float r = __expf(m - nm);
            float p = __expf(part - nm);
            denom = denom * r + p;
#pragma unroll
            for (int k = 0; k < 6; k++) acc[k] = fmaf(p, xs[k], acc[k] * r);
            m = nm;
        } else {
            float p = __expf(part - m);
            denom += p;
#pragma unroll
            for (int k = 0; k < 6; k++) acc[k] = fmaf(p, xs[k], acc[k]);
        }
    }

    float inv = 1.f / (denom + 1e-16f);
    float v[6];
    float s1 = 0.f;
#pragma unroll
    for (int k = 0; k < 6; k++) { v[k] = acc[k] * inv + bias[c0 + k]; s1 += v[k]; }
#pragma unroll
    for (int o = 1; o < 64; o <<= 1) s1 += __shfl_xor(s1, o, 64);
    float mu = s1 * (1.f / 384.f);
    float s2 = 0.f;
#pragma unroll
    for (int k = 0; k < 6; k++) { float d = v[k] - mu; s2 += d * d; }
#pragma unroll
    for (int o = 1; o < 64; o <<= 1) s2 += __shfl_xor(s2, o, 64);
    float rstd = rsqrtf(s2 * (1.f / 384.f) + 1e-5f);

    float ov[6];
#pragma unroll
    for (int k = 0; k < 6; k++) {
        float y = (v[k] - mu) * rstd * gamma[c0 + k] + beta[c0 + k];
        ov[k] = y > 0.f ? y : expm1f(y);
    }
    u32t w0 = (u32t)f2bf(ov[0]) | ((u32t)f2bf(ov[1]) << 16);
    u32t w1 = (u32t)f2bf(ov[2]) | ((u32t)f2bf(ov[3]) << 16);
    u32t w2 = (u32t)f2bf(ov[4]) | ((u32t)f2bf(ov[5]) << 16);
    u32t* hp = (u32t*)Hout + (size_t)node * 192 + lo3;
    hp[0] = w0; hp[1] = w1; hp[2] = w2;
}

// ============================ LN + Wc2 output ============================

__global__ __launch_bounds__(256) void k_lnout(const float* __restrict__ Yh,
                                               const float* __restrict__ gc,
                                               const float* __restrict__ bec,
                                               const float* __restrict__ Wc2,
                                               const float* __restrict__ bc2,
                                               float* __restrict__ out, int N) {
    __shared__ float w2[CH * NCLS];
    __shared__ float ln[8][CH];
    int t = threadIdx.x;
    int g = t >> 5, tl = t & 31;
    int node = blockIdx.x * 8 + g;

    for (int i = t; i < CH * NCLS; i += 256) w2[i] = Wc2[i];

    if (node < N) {
        const float* yp = Yh + (size_t)node * CH;
        float y0 = yp[tl], y1 = yp[32 + tl], y2 = yp[64 + tl];
        float s = y0 + y1 + y2;
#pragma unroll
        for (int o = 1; o < 32; o <<= 1) s += __shfl_xor(s, o, 32);
        float mu = s * (1.f / CH);
        float d0 = y0 - mu, d1 = y1 - mu, d2 = y2 - mu;
        float q = d0 * d0 + d1 * d1 + d2 * d2;
#pragma unroll
        for (int o = 1; o < 32; o <<= 1) q += __shfl_xor(q, o, 32);
        float rstd = rsqrtf(q * (1.f / CH) + 1e-5f);
        ln[g][tl]      = d0 * rstd * gc[tl]      + bec[tl];
        ln[g][32 + tl] = d1 * rstd * gc[32 + tl] + bec[32 + tl];
        ln[g][64 + tl] = d2 * rstd * gc[64 + tl] + bec[64 + tl];
    }
    __syncthreads();

    if (node < N && tl < NCLS) {
        float o = bc2[tl];
        for (int c = 0; c < CH; c++) o += ln[g][c] * w2[c * NCLS + tl];
        out[(size_t)node * NCLS + tl] = o;
    }
}

// ============================ launch ============================

extern "C" void kernel_launch(void* const* d_in, const int* in_sizes, int n_in,
                              void* d_out, int out_size, void* d_ws, size_t ws_size,
                              hipStream_t stream) {
    const float* x        = (const float*)d_in[0];
    const int*   eidx     = (const int*)d_in[1];
    const float* Wsrc[3]  = {(const float*)d_in[2],  (const float*)d_in[8],  (const float*)d_in[14]};
    const float* Wdst[3]  = {(const float*)d_in[3],  (const float*)d_in[9],  (const float*)d_in[15]};
    const float* attw[3]  = {(const float*)d_in[4],  (const float*)d_in[10], (const float*)d_in[16]};
    const float* bia[3]   = {(const float*)d_in[5],  (const float*)d_in[11], (const float*)d_in[17]};
    const float* gam[3]   = {(const float*)d_in[6],  (const float*)d_in[12], (const float*)d_in[18]};
    const float* bet[3]   = {(const float*)d_in[7],  (const float*)d_in[13], (const float*)d_in[19]};
    const float* Wc1 = (const float*)d_in[20];
    const float* bc1 = (const float*)d_in[21];
    const float* gc  = (const float*)d_in[22];
    const float* bec = (const float*)d_in[23];
    const float* Wc2 = (const float*)d_in[24];
    const float* bc2 = (const float*)d_in[25];

    const int N = in_sizes[0] / FIN;
    const int E = in_sizes[1] / 2;
    const int Mpad = ((N + 127) / 128) * 128;
    const int* srcp = eidx;
    const int* dstp = eidx + E;

    // ---- workspace layout ----
    u16t* xbf  = (u16t*)d_ws;                         // Mpad*96
    u16t* XSXD = xbf + (size_t)Mpad * 96;             // Mpad*768 (XS||XD per row)
    u16t* Hbf  = XSXD + (size_t)Mpad * 768;           // Mpad*384
    u16t* WT0s = Hbf + (size_t)Mpad * D;              // [768][96] cat (s then d)
    u16t* WT0d = WT0s + 384 * 96;
    u16t* WT1s = WT0d + 384 * 96;                     // [768][384] cat
    u16t* WT1d = WT1s + 384 * 384;
    u16t* WT2s = WT1d + 384 * 384;                    // [768][384] cat
    u16t* WT2d = WT2s + 384 * 384;
    u16t* Wc1T = WT2d + 384 * 384;                    // [128][384]
    float* Yh  = (float*)(Wc1T + 128 * 384);          // Mpad*96 f32
    int* offs    = (int*)(Yh + (size_t)Mpad * CH);
    int* cursor  = offs + (N + 1);
    int* deg     = cursor + (N + 1);
    int* bsum    = deg + N;
    int* csr_srcb = bsum + 512;

    const int nb = (N + 255) / 256;

    // ---- CSR build ----
    k_zero<<<nb, 256, 0, stream>>>(deg, N);
    k_hist<<<(E + 255) / 256, 256, 0, stream>>>(dstp, deg, E);
    k_scan1<<<nb, 256, 0, stream>>>(deg, offs, bsum, N);
    k_scan2<<<1, 256, 0, stream>>>(bsum, nb, offs, N);
    k_scan3<<<nb, 256, 0, stream>>>(offs, cursor, bsum, N);
    k_scatter<<<(E + 255) / 256, 256, 0, stream>>>(srcp, dstp, cursor, csr_srcb, E);

    // ---- weight/input conversion ----
    k_cvt_x<<<(N * 96 + 255) / 256, 256, 0, stream>>>(x, xbf, N);
    k_cvt_wT<<<(D * 96 + 255) / 256, 256, 0, stream>>>(Wsrc[0], WT0s, FIN, 96);
    k_cvt_wT<<<(D * 96 + 255) / 256, 256, 0, stream>>>(Wdst[0], WT0d, FIN, 96);
    k_cvt_wT<<<(D * D + 255) / 256, 256, 0, stream>>>(Wsrc[1], WT1s, D, D);
    k_cvt_wT<<<(D * D + 255) / 256, 256, 0, stream>>>(Wdst[1], WT1d, D, D);
    k_cvt_wT<<<(D * D + 255) / 256, 256, 0, stream>>>(Wsrc[2], WT2s, D, D);
    k_cvt_wT<<<(D * D + 255) / 256, 256, 0, stream>>>(Wdst[2], WT2d, D, D);
    k_cvt_wc1T<<<(128 * D + 255) / 256, 256, 0, stream>>>(Wc1, Wc1T);

    dim3 gmm(Mpad / 128, 768 / 128);   // both Wsrc and Wdst halves in one launch
    int gatGrid = (N + 3) / 4;

    // ---- layer 0 (Kp = 96) ----
    k_mm<<<gmm, 256, 0, stream>>>(xbf, WT0s, XSXD, 96, 768);
    k_gat<<<gatGrid, 256, 0, stream>>>((const u32t*)XSXD, attw[0], bia[0], gam[0], bet[0],
                                       offs, csr_srcb, Hbf, N);
    // ---- layer 1 (Kp = 384) ----
    k_mm<<<gmm, 256, 0, stream>>>(Hbf, WT1s, XSXD, D, 768);
    k_gat<<<gatGrid, 256, 0, stream>>>((const u32t*)XSXD, attw[1], bia[1], gam[1], bet[1],
                                       offs, csr_srcb, Hbf, N);
    // ---- layer 2 (Kp = 384) ----
    k_mm<<<gmm, 256, 0, stream>>>(Hbf, WT2s, XSXD, D, 768);
    k_gat<<<gatGrid, 256, 0, stream>>>((const u32t*)XSXD, attw[2], bia[2], gam[2], bet[2],
                                       offs, csr_srcb, Hbf, N);

    // ---- classifier head: MFMA GEMM + LN/out ----
    k_mmh<<<Mpad / 128, 256, 0, stream>>>(Hbf, Wc1T, bc1, Yh);
    k_lnout<<<(N + 7) / 8, 256, 0, stream>>>(Yh, gc, bec, Wc2, bc2,
                                             (float*)d_out, N);
}

// Round 11
// 749.843 us; speedup vs baseline: 2.6696x; 1.1542x over previous
//
#include <hip/hip_runtime.h>
#include <math.h>

#define D 384
#define NCLS 20
#define FIN 80
#define CH 96

typedef unsigned int u32t;
typedef unsigned short u16t;
typedef __attribute__((ext_vector_type(8))) short bf16x8;
typedef __attribute__((ext_vector_type(4))) float f32x4;

__device__ __forceinline__ u16t f2bf(float f) {
    u32t b = __float_as_uint(f);
    u32t r = (b + 0x7FFFu + ((b >> 16) & 1u)) >> 16;
    return (u16t)r;
}
__device__ __forceinline__ float bfl(u32t u) { return __uint_as_float(u << 16); }
__device__ __forceinline__ float bfh(u32t u) { return __uint_as_float(u & 0xFFFF0000u); }

#define GLOAD16(g, l)                                                            \
    __builtin_amdgcn_global_load_lds(                                            \
        (const __attribute__((address_space(1))) void*)(g),                      \
        (__attribute__((address_space(3))) void*)(l), 16, 0, 0)

// ============================ CSR build ============================

__global__ void k_zero(int* p, int n) {
    int i = blockIdx.x * blockDim.x + threadIdx.x;
    if (i < n) p[i] = 0;
}

__global__ void k_hist(const int* __restrict__ dst, int* __restrict__ deg, int E) {
    int i = blockIdx.x * blockDim.x + threadIdx.x;
    if (i < E) atomicAdd(&deg[dst[i]], 1);
}

__global__ __launch_bounds__(256) void k_scan1(const int* __restrict__ deg,
                                               int* __restrict__ offs,
                                               int* __restrict__ bsum, int n) {
    __shared__ int sh[256];
    int t = threadIdx.x, i = blockIdx.x * 256 + t;
    int v = (i < n) ? deg[i] : 0;
    sh[t] = v;
    __syncthreads();
    for (int o = 1; o < 256; o <<= 1) {
        int a = (t >= o) ? sh[t - o] : 0;
        __syncthreads();
        sh[t] += a;
        __syncthreads();
    }
    if (i < n) offs[i] = sh[t] - v;
    if (t == 255) bsum[blockIdx.x] = sh[255];
}

__global__ __launch_bounds__(256) void k_scan2(int* __restrict__ bsum, int nb,
                                               int* __restrict__ offs, int n) {
    __shared__ int sh[256];
    int t = threadIdx.x;
    int v = (t < nb) ? bsum[t] : 0;
    sh[t] = v;
    __syncthreads();
    for (int o = 1; o < 256; o <<= 1) {
        int a = (t >= o) ? sh[t - o] : 0;
        __syncthreads();
        sh[t] += a;
        __syncthreads();
    }
    if (t < nb) bsum[t] = sh[t] - v;
    if (t == 255) offs[n] = sh[255];
}

__global__ __launch_bounds__(256) void k_scan3(int* __restrict__ offs,
                                               int* __restrict__ cursor,
                                               const int* __restrict__ bsum, int n) {
    int i = blockIdx.x * 256 + threadIdx.x;
    if (i < n) {
        int o = offs[i] + bsum[blockIdx.x];
        offs[i] = o;
        cursor[i] = o;
    }
}

// stores PRE-MULTIPLIED source row offset (src * 384 u32 = row in XSXD)
__global__ void k_scatter(const int* __restrict__ src, const int* __restrict__ dst,
                          int* __restrict__ cursor, int* __restrict__ csr_srcb, int E) {
    int i = blockIdx.x * blockDim.x + threadIdx.x;
    if (i < E) {
        int p = atomicAdd(&cursor[dst[i]], 1);
        csr_srcb[p] = src[i] * 384;
    }
}

// ============================ merged fp32 -> bf16 converter ============================
// seg0: x [N][80] -> xbf [N][96] (pad 0)
// seg1/2: Wsrc0/Wdst0 [80][384] -> WT [384][96]T (pad 0)
// seg3..6: Wsrc1/Wdst1/Wsrc2/Wdst2 [384][384] -> WT [384][384]T
// seg7: Wc1 [384][96] -> Wc1T [128][384]T (pad 0)

__global__ __launch_bounds__(256) void k_cvt_all(
    const float* __restrict__ x,
    const float* __restrict__ Ws0, const float* __restrict__ Wd0,
    const float* __restrict__ Ws1, const float* __restrict__ Wd1,
    const float* __restrict__ Ws2, const float* __restrict__ Wd2,
    const float* __restrict__ Wc1,
    u16t* __restrict__ xbf,
    u16t* __restrict__ WT0s, u16t* __restrict__ WT0d,
    u16t* __restrict__ WT1s, u16t* __restrict__ WT1d,
    u16t* __restrict__ WT2s, u16t* __restrict__ WT2d,
    u16t* __restrict__ Wc1T, int N) {
    const int s96 = 384 * 96, s384 = 384 * 384, sc1 = 128 * 384;
    int i = blockIdx.x * 256 + threadIdx.x;

    int n0 = N * 96;
    if (i < n0) {
        int r = i / 96, c = i - r * 96;
        xbf[i] = f2bf(c < FIN ? x[r * FIN + c] : 0.f);
        return;
    }
    i -= n0;
    if (i < 2 * s96) {
        const float* W = (i < s96) ? Ws0 : Wd0;
        u16t* O = (i < s96) ? WT0s : WT0d;
        int k2 = (i < s96) ? i : i - s96;
        int c = k2 / 96, k = k2 - c * 96;
        O[k2] = f2bf(k < FIN ? W[(size_t)k * D + c] : 0.f);
        return;
    }
    i -= 2 * s96;
    if (i < 4 * s384) {
        int w = i / s384, k2 = i - w * s384;
        const float* W = (w == 0) ? Ws1 : (w == 1) ? Wd1 : (w == 2) ? Ws2 : Wd2;
        u16t* O = (w == 0) ? WT1s : (w == 1) ? WT1d : (w == 2) ? WT2s : WT2d;
        int c = k2 / 384, k = k2 - c * 384;
        O[k2] = f2bf(W[(size_t)k * D + c]);
        return;
    }
    i -= 4 * s384;
    if (i < sc1) {
        int c = i / D, k = i - c * D;
        Wc1T[i] = f2bf(c < CH ? Wc1[(size_t)k * CH + c] : 0.f);
    }
}

// ============================ bf16 MFMA GEMM ============================
// C[Mpad, ostride](bf16): C = A[Mpad,Kp] * BT[NB*128, Kp]
// 128x128 tile, BK=32, 4 waves (2x2 quadrants of 64x64), mfma 16x16x32 bf16.

__global__ __launch_bounds__(256) void k_mm(const u16t* __restrict__ A,
                                            const u16t* __restrict__ BT,
                                            u16t* __restrict__ C, int Kp, int ostride) {
    __shared__ u16t Al[4][128][8];
    __shared__ u16t Bl[4][128][8];
    const int t = threadIdx.x;
    const int wave = t >> 6, lane = t & 63;
    const int wr = wave >> 1, wc = wave & 1;
    const int bm0 = blockIdx.x * 128;
    const int bn0 = blockIdx.y * 128;
    const int col16 = lane & 15, kc = lane >> 4;

    f32x4 acc[4][4] = {};

    const u16t* asrc0 = A + (size_t)(bm0 + lane) * Kp + wave * 8;
    const u16t* asrc1 = A + (size_t)(bm0 + 64 + lane) * Kp + wave * 8;
    const u16t* bsrc0 = BT + (size_t)(bn0 + lane) * Kp + wave * 8;
    const u16t* bsrc1 = BT + (size_t)(bn0 + 64 + lane) * Kp + wave * 8;
    u16t* alds0 = &Al[wave][0][0];
    u16t* alds1 = &Al[wave][64][0];
    u16t* blds0 = &Bl[wave][0][0];
    u16t* blds1 = &Bl[wave][64][0];

    for (int k0 = 0; k0 < Kp; k0 += 32) {
        GLOAD16(asrc0 + k0, alds0);
        GLOAD16(asrc1 + k0, alds1);
        GLOAD16(bsrc0 + k0, blds0);
        GLOAD16(bsrc1 + k0, blds1);
        __syncthreads();

        bf16x8 a[4], b[4];
#pragma unroll
        for (int m = 0; m < 4; m++)
            a[m] = *(const bf16x8*)&Al[kc][wr * 64 + m * 16 + col16][0];
#pragma unroll
        for (int n = 0; n < 4; n++)
            b[n] = *(const bf16x8*)&Bl[kc][wc * 64 + n * 16 + col16][0];
#pragma unroll
        for (int m = 0; m < 4; m++)
#pragma unroll
            for (int n = 0; n < 4; n++)
                acc[m][n] = __builtin_amdgcn_mfma_f32_16x16x32_bf16(
                    a[m], b[n], acc[m][n], 0, 0, 0);
        __syncthreads();
    }

#pragma unroll
    for (int m = 0; m < 4; m++) {
#pragma unroll
        for (int n = 0; n < 4; n++) {
#pragma unroll
            for (int j = 0; j < 4; j++) {
                int row = bm0 + wr * 64 + m * 16 + (lane >> 4) * 4 + j;
                int col = bn0 + wc * 64 + n * 16 + col16;
                C[(size_t)row * ostride + col] = f2bf(acc[m][n][j]);
            }
        }
    }
}

// ============================ head GEMM: Yh[Mpad,96] = relu(Hbf @ Wc1 + bc1) ============================

__global__ __launch_bounds__(256) void k_mmh(const u16t* __restrict__ A,
                                             const u16t* __restrict__ BT,
                                             const float* __restrict__ bc1,
                                             float* __restrict__ Yh) {
    __shared__ u16t Al[4][128][8];
    __shared__ u16t Bl[4][128][8];
    const int t = threadIdx.x;
    const int wave = t >> 6, lane = t & 63;
    const int wr = wave >> 1, wc = wave & 1;
    const int bm0 = blockIdx.x * 128;
    const int col16 = lane & 15, kc = lane >> 4;

    f32x4 acc[4][4] = {};

    const u16t* asrc0 = A + (size_t)(bm0 + lane) * D + wave * 8;
    const u16t* asrc1 = A + (size_t)(bm0 + 64 + lane) * D + wave * 8;
    const u16t* bsrc0 = BT + (size_t)lane * D + wave * 8;
    const u16t* bsrc1 = BT + (size_t)(64 + lane) * D + wave * 8;
    u16t* alds0 = &Al[wave][0][0];
    u16t* alds1 = &Al[wave][64][0];
    u16t* blds0 = &Bl[wave][0][0];
    u16t* blds1 = &Bl[wave][64][0];

    for (int k0 = 0; k0 < D; k0 += 32) {
        GLOAD16(asrc0 + k0, alds0);
        GLOAD16(asrc1 + k0, alds1);
        GLOAD16(bsrc0 + k0, blds0);
        GLOAD16(bsrc1 + k0, blds1);
        __syncthreads();

        bf16x8 a[4], b[4];
#pragma unroll
        for (int m = 0; m < 4; m++)
            a[m] = *(const bf16x8*)&Al[kc][wr * 64 + m * 16 + col16][0];
#pragma unroll
        for (int n = 0; n < 4; n++)
            b[n] = *(const bf16x8*)&Bl[kc][wc * 64 + n * 16 + col16][0];
#pragma unroll
        for (int m = 0; m < 4; m++)
#pragma unroll
            for (int n = 0; n < 4; n++)
                acc[m][n] = __builtin_amdgcn_mfma_f32_16x16x32_bf16(
                    a[m], b[n], acc[m][n], 0, 0, 0);
        __syncthreads();
    }

#pragma unroll
    for (int m = 0; m < 4; m++) {
#pragma unroll
        for (int n = 0; n < 4; n++) {
            int col = wc * 64 + n * 16 + col16;
            if (col < CH) {
                float bc = bc1[col];
#pragma unroll
                for (int j = 0; j < 4; j++) {
                    int row = bm0 + wr * 64 + m * 16 + (lane >> 4) * 4 + j;
                    Yh[(size_t)row * CH + col] = fmaxf(acc[m][n][j] + bc, 0.f);
                }
            }
        }
    }
}

// ============================ fused GAT node kernel ============================
// XSXD [Mpad][768] bf16: cols 0..383 = Wsrc*h, 384..767 = Wdst*h.
// One wave per node; lane owns 6 channels. Scores in exp2 domain (att
// pre-scaled by log2e). Edge indices bulk-loaded 64 at a time (1 coalesced
// load), broadcast per edge via readlane -> SGPR base addressing. Next
// edge's 12B row slice prefetched before current edge's math (depth-1 SW
// pipeline, loads issued above the defer-max branch).

__global__ __launch_bounds__(256) void k_gat(const u32t* __restrict__ XSXD,
                                             const float* __restrict__ att,
                                             const float* __restrict__ bias,
                                             const float* __restrict__ gamma,
                                             const float* __restrict__ beta,
                                             const int* __restrict__ offs,
                                             const int* __restrict__ csr_srcb,
                                             u16t* __restrict__ Hout,
                                             int N) {
    int wave = threadIdx.x >> 6;
    int lane = threadIdx.x & 63;
    int node = blockIdx.x * 4 + wave;
    if (node >= N) return;
    int c0 = lane * 6;
    int lo3 = lane * 3;

    const u32t* xdp = XSXD + (size_t)node * 384 + 192 + lo3;
    u32t d0 = xdp[0], d1 = xdp[1], d2 = xdp[2];
    float xd[6] = {bfl(d0), bfh(d0), bfl(d1), bfh(d1), bfl(d2), bfh(d2)};
    float attr[6];
#pragma unroll
    for (int k = 0; k < 6; k++) attr[k] = att[c0 + k] * 1.44269504f;  // log2 e

    float m = -INFINITY, denom = 0.f;
    float acc[6] = {0.f, 0.f, 0.f, 0.f, 0.f, 0.f};
    int e0 = offs[node], e1 = offs[node + 1];

    for (int base = e0; base < e1; base += 64) {
        int cnt = min(64, e1 - base);
        u32t midx = (lane < cnt) ? (u32t)csr_srcb[base + lane] : 0u;
        u32t off = __builtin_amdgcn_readlane(midx, 0);
        const u32t* p = XSXD + off + lo3;
        u32t a0 = p[0], a1 = p[1], a2 = p[2];

        for (int j = 0; j < cnt; j++) {
            u32t b0 = a0, b1 = a1, b2 = a2;
            if (j + 1 < cnt) {
                u32t offn = __builtin_amdgcn_readlane(midx, j + 1);
                const u32t* pn = XSXD + offn + lo3;
                a0 = pn[0]; a1 = pn[1]; a2 = pn[2];
            }
            float xs[6] = {bfl(b0), bfh(b0), bfl(b1), bfh(b1), bfl(b2), bfh(b2)};
            float part = 0.f;
#pragma unroll
            for (int k = 0; k < 6; k++) {
                float v = xs[k] + xd[k];
                part = fmaf(fmaxf(v, 0.2f * v), attr[k], part);
            }
#pragma unroll
            for (int o = 1; o < 16; o <<= 1) part += __shfl_xor(part, o, 64);

            if (__builtin_expect(__any(part - m > 8.0f), 0)) {
                float nm = fmaxf(m, part);
                float r = __builtin_amdgcn_exp2f(m - nm);
                float pp = __builtin_amdgcn_exp2f(part - nm);
                denom = denom * r + pp;
#pragma unroll
                for (int k = 0; k < 6; k++) acc[k] = fmaf(pp, xs[k], acc[k] * r);
                m = nm;
            } else {
                float pp = __builtin_amdgcn_exp2f(part - m);
                denom += pp;
#pragma unroll
                for (int k = 0; k < 6; k++) acc[k] = fmaf(pp, xs[k], acc[k]);
            }
        }
    }

    float inv = 1.f / (denom + 1e-16f);
    float v[6];
    float s1 = 0.f;
#pragma unroll
    for (int k = 0; k < 6; k++) { v[k] = acc[k] * inv + bias[c0 + k]; s1 += v[k]; }
#pragma unroll
    for (int o = 1; o < 64; o <<= 1) s1 += __shfl_xor(s1, o, 64);
    float mu = s1 * (1.f / 384.f);
    float s2 = 0.f;
#pragma unroll
    for (int k = 0; k < 6; k++) { float d = v[k] - mu; s2 += d * d; }
#pragma unroll
    for (int o = 1; o < 64; o <<= 1) s2 += __shfl_xor(s2, o, 64);
    float rstd = rsqrtf(s2 * (1.f / 384.f) + 1e-5f);

    float ov[6];
#pragma unroll
    for (int k = 0; k < 6; k++) {
        float y = (v[k] - mu) * rstd * gamma[c0 + k] + beta[c0 + k];
        ov[k] = y > 0.f ? y : __expf(y) - 1.f;   // fast ELU (|err| ~1e-7)
    }
    u32t w0 = (u32t)f2bf(ov[0]) | ((u32t)f2bf(ov[1]) << 16);
    u32t w1 = (u32t)f2bf(ov[2]) | ((u32t)f2bf(ov[3]) << 16);
    u32t w2 = (u32t)f2bf(ov[4]) | ((u32t)f2bf(ov[5]) << 16);
    u32t* hp = (u32t*)Hout + (size_t)node * 192 + lo3;
    hp[0] = w0; hp[1] = w1; hp[2] = w2;
}

// ============================ LN + Wc2 output ============================

__global__ __launch_bounds__(256) void k_lnout(const float* __restrict__ Yh,
                                               const float* __restrict__ gc,
                                               const float* __restrict__ bec,
                                               const float* __restrict__ Wc2,
                                               const float* __restrict__ bc2,
                                               float* __restrict__ out, int N) {
    __shared__ float w2[CH * NCLS];
    __shared__ float ln[8][CH];
    int t = threadIdx.x;
    int g = t >> 5, tl = t & 31;
    int node = blockIdx.x * 8 + g;

    for (int i = t; i < CH * NCLS; i += 256) w2[i] = Wc2[i];

    if (node < N) {
        const float* yp = Yh + (size_t)node * CH;
        float y0 = yp[tl], y1 = yp[32 + tl], y2 = yp[64 + tl];
        float s = y0 + y1 + y2;
#pragma unroll
        for (int o = 1; o < 32; o <<= 1) s += __shfl_xor(s, o, 32);
        float mu = s * (1.f / CH);
        float d0 = y0 - mu, d1 = y1 - mu, d2 = y2 - mu;
        float q = d0 * d0 + d1 * d1 + d2 * d2;
#pragma unroll
        for (int o = 1; o < 32; o <<= 1) q += __shfl_xor(q, o, 32);
        float rstd = rsqrtf(q * (1.f / CH) + 1e-5f);
        ln[g][tl]      = d0 * rstd * gc[tl]      + bec[tl];
        ln[g][32 + tl] = d1 * rstd * gc[32 + tl] + bec[32 + tl];
        ln[g][64 + tl] = d2 * rstd * gc[64 + tl] + bec[64 + tl];
    }
    __syncthreads();

    if (node < N && tl < NCLS) {
        float o = bc2[tl];
        for (int c = 0; c < CH; c++) o += ln[g][c] * w2[c * NCLS + tl];
        out[(size_t)node * NCLS + tl] = o;
    }
}

// ============================ launch ============================

extern "C" void kernel_launch(void* const* d_in, const int* in_sizes, int n_in,
                              void* d_out, int out_size, void* d_ws, size_t ws_size,
                              hipStream_t stream) {
    const float* x        = (const float*)d_in[0];
    const int*   eidx     = (const int*)d_in[1];
    const float* Wsrc[3]  = {(const float*)d_in[2],  (const float*)d_in[8],  (const float*)d_in[14]};
    const float* Wdst[3]  = {(const float*)d_in[3],  (const float*)d_in[9],  (const float*)d_in[15]};
    const float* attw[3]  = {(const float*)d_in[4],  (const float*)d_in[10], (const float*)d_in[16]};
    const float* bia[3]   = {(const float*)d_in[5],  (const float*)d_in[11], (const float*)d_in[17]};
    const float* gam[3]   = {(const float*)d_in[6],  (const float*)d_in[12], (const float*)d_in[18]};
    const float* bet[3]   = {(const float*)d_in[7],  (const float*)d_in[13], (const float*)d_in[19]};
    const float* Wc1 = (const float*)d_in[20];
    const float* bc1 = (const float*)d_in[21];
    const float* gc  = (const float*)d_in[22];
    const float* bec = (const float*)d_in[23];
    const float* Wc2 = (const float*)d_in[24];
    const float* bc2 = (const float*)d_in[25];

    const int N = in_sizes[0] / FIN;
    const int E = in_sizes[1] / 2;
    const int Mpad = ((N + 127) / 128) * 128;
    const int* srcp = eidx;
    const int* dstp = eidx + E;

    // ---- workspace layout ----
    u16t* xbf  = (u16t*)d_ws;                         // Mpad*96
    u16t* XSXD = xbf + (size_t)Mpad * 96;             // Mpad*768 (XS||XD per row)
    u16t* Hbf  = XSXD + (size_t)Mpad * 768;           // Mpad*384
    u16t* WT0s = Hbf + (size_t)Mpad * D;              // [384][96]
    u16t* WT0d = WT0s + 384 * 96;
    u16t* WT1s = WT0d + 384 * 96;                     // [384][384]
    u16t* WT1d = WT1s + 384 * 384;
    u16t* WT2s = WT1d + 384 * 384;
    u16t* WT2d = WT2s + 384 * 384;
    u16t* Wc1T = WT2d + 384 * 384;                    // [128][384]
    float* Yh  = (float*)(Wc1T + 128 * 384);          // Mpad*96 f32
    int* offs    = (int*)(Yh + (size_t)Mpad * CH);
    int* cursor  = offs + (N + 1);
    int* deg     = cursor + (N + 1);
    int* bsum    = deg + N;
    int* csr_srcb = bsum + 512;

    const int nb = (N + 255) / 256;

    // ---- CSR build ----
    k_zero<<<nb, 256, 0, stream>>>(deg, N);
    k_hist<<<(E + 255) / 256, 256, 0, stream>>>(dstp, deg, E);
    k_scan1<<<nb, 256, 0, stream>>>(deg, offs, bsum, N);
    k_scan2<<<1, 256, 0, stream>>>(bsum, nb, offs, N);
    k_scan3<<<nb, 256, 0, stream>>>(offs, cursor, bsum, N);
    k_scatter<<<(E + 255) / 256, 256, 0, stream>>>(srcp, dstp, cursor, csr_srcb, E);

    // ---- merged weight/input conversion ----
    {
        long total = (long)N * 96 + 2L * (384 * 96) + 4L * (384 * 384) + 128L * 384;
        int cblocks = (int)((total + 255) / 256);
        k_cvt_all<<<cblocks, 256, 0, stream>>>(
            x, Wsrc[0], Wdst[0], Wsrc[1], Wdst[1], Wsrc[2], Wdst[2], Wc1,
            xbf, WT0s, WT0d, WT1s, WT1d, WT2s, WT2d, Wc1T, N);
    }

    dim3 gmm(Mpad / 128, 768 / 128);   // Wsrc and Wdst halves in one launch
    int gatGrid = (N + 3) / 4;

    // ---- layer 0 (Kp = 96) ----
    k_mm<<<gmm, 256, 0, stream>>>(xbf, WT0s, XSXD, 96, 768);
    k_gat<<<gatGrid, 256, 0, stream>>>((const u32t*)XSXD, attw[0], bia[0], gam[0], bet[0],
                                       offs, csr_srcb, Hbf, N);
    // ---- layer 1 (Kp = 384) ----
    k_mm<<<gmm, 256, 0, stream>>>(Hbf, WT1s, XSXD, D, 768);
    k_gat<<<gatGrid, 256, 0, stream>>>((const u32t*)XSXD, attw[1], bia[1], gam[1], bet[1],
                                       offs, csr_srcb, Hbf, N);
    // ---- layer 2 (Kp = 384) ----
    k_mm<<<gmm, 256, 0, stream>>>(Hbf, WT2s, XSXD, D, 768);
    k_gat<<<gatGrid, 256, 0, stream>>>((const u32t*)XSXD, attw[2], bia[2], gam[2], bet[2],
                                       offs, csr_srcb, Hbf, N);

    // ---- classifier head: MFMA GEMM + LN/out ----
    k_mmh<<<Mpad / 128, 256, 0, stream>>>(Hbf, Wc1T, bc1, Yh);
    k_lnout<<<(N + 7) / 8, 256, 0, stream>>>(Yh, gc, bec, Wc2, bc2,
                                             (float*)d_out, N);
}